// Round 9
// baseline (563.897 us; speedup 1.0000x reference)
//
#include <hip/hip_runtime.h>

typedef unsigned short u16;
typedef unsigned int   u32;
typedef _Float16 f16;
typedef f16 h2 __attribute__((ext_vector_type(2)));
typedef f16 h4 __attribute__((ext_vector_type(4)));
typedef f16 h8 __attribute__((ext_vector_type(8)));

#define T_    120
#define D_    64
#define DOUT_ 31
#define KROW_ 68    // f16/row: 136B, 8B-aligned; 34-word stride -> 2-way bank alias (free)
#define VROW_ 132   // f16/row: 264B, 8B-aligned; 2-way (free)
#define WP_   68    // LDS weight-row stride (f16): 8B-aligned, 2-way

#if defined(__has_builtin)
#if __has_builtin(__builtin_amdgcn_fdot2)
#define DOT2(a,b,c) __builtin_amdgcn_fdot2((a),(b),(c),false)
#endif
#endif
#ifndef DOT2
#define DOT2(a,b,c) ((float)(a).x*(float)(b).x + ((float)(a).y*(float)(b).y + (c)))
#endif
#define SHV(x,i,j) __builtin_shufflevector((x),(x),(i),(j))

__device__ __forceinline__ h2 pk(float a, float b){
#if defined(__has_builtin) && __has_builtin(__builtin_amdgcn_cvt_pkrtz)
  return __builtin_bit_cast(h2, __builtin_amdgcn_cvt_pkrtz(a, b));
#else
  h2 r; r.x = (f16)a; r.y = (f16)b; return r;
#endif
}
__device__ __forceinline__ float2 bp2(u32 u){
  float2 r; r.x = __uint_as_float(u << 16); r.y = __uint_as_float(u & 0xffff0000u); return r;
}
__device__ __forceinline__ u16 f2bu(float f){
  u32 u = __float_as_uint(f);
  u32 r = u + 0x7fffu + ((u >> 16) & 1u);
  return (u16)(r >> 16);
}
#define WSYNC() do{ __asm__ __volatile__("" ::: "memory"); __builtin_amdgcn_wave_barrier(); }while(0)

__device__ __forceinline__ float dpp_sum(float x){
  int t;
  t = __builtin_amdgcn_update_dpp(0, __float_as_int(x), 0x111, 0xf, 0xf, true); x += __int_as_float(t);
  t = __builtin_amdgcn_update_dpp(0, __float_as_int(x), 0x112, 0xf, 0xf, true); x += __int_as_float(t);
  t = __builtin_amdgcn_update_dpp(0, __float_as_int(x), 0x114, 0xf, 0xf, true); x += __int_as_float(t);
  t = __builtin_amdgcn_update_dpp(0, __float_as_int(x), 0x118, 0xf, 0xf, true); x += __int_as_float(t);
  t = __builtin_amdgcn_update_dpp(0, __float_as_int(x), 0x142, 0xf, 0xf, true); x += __int_as_float(t);
  t = __builtin_amdgcn_update_dpp(0, __float_as_int(x), 0x143, 0xf, 0xf, true); x += __int_as_float(t);
  return __int_as_float(__builtin_amdgcn_readlane(__float_as_int(x), 63));
}
__device__ __forceinline__ float dpp_max_pos(float x){   // requires true max > 0 (k_final only)
  int t;
  t = __builtin_amdgcn_update_dpp(0, __float_as_int(x), 0x111, 0xf, 0xf, true); x = fmaxf(x, __int_as_float(t));
  t = __builtin_amdgcn_update_dpp(0, __float_as_int(x), 0x112, 0xf, 0xf, true); x = fmaxf(x, __int_as_float(t));
  t = __builtin_amdgcn_update_dpp(0, __float_as_int(x), 0x114, 0xf, 0xf, true); x = fmaxf(x, __int_as_float(t));
  t = __builtin_amdgcn_update_dpp(0, __float_as_int(x), 0x118, 0xf, 0xf, true); x = fmaxf(x, __int_as_float(t));
  t = __builtin_amdgcn_update_dpp(0, __float_as_int(x), 0x142, 0xf, 0xf, true); x = fmaxf(x, __int_as_float(t));
  t = __builtin_amdgcn_update_dpp(0, __float_as_int(x), 0x143, 0xf, 0xf, true); x = fmaxf(x, __int_as_float(t));
  return __int_as_float(__builtin_amdgcn_readlane(__float_as_int(x), 63));
}
__device__ __forceinline__ float pe_val(int row, int i){
  const float coef = -0.28782313662425574f; // -ln(10000)/32
  int p = row % 10;
  float dv  = __expf((float)(i >> 1) * coef);
  float ang = (float)p * dv;
  return (i & 1) ? __cosf(ang) : __sinf(ang);
}
__device__ __forceinline__ void loadrow32(h2* dst, const float* row){
  #pragma unroll
  for (int r = 0; r < 16; ++r){
    float4 f = ((const float4*)row)[r];
    dst[2*r]   = pk(f.x, f.y);
    dst[2*r+1] = pk(f.z, f.w);
  }
}

// ---------- kernel PRE ----------
// blocks 0-119: mem+cross.  block 120: bf16 prep for k_final + ALL fusion precompute:
//   M = Wm@Wr, bMs = Wm@br + bm + style, xb[p] = bMs + pe_p,
//   QM=Wq@M, KM, VM, qb/kb/vb[p] = W?@xb[p] + b?, and q0,k0,v0,x0.
__global__ __launch_bounds__(256) void k_pre(const float* __restrict__ audio,
                                             const float* __restrict__ Wa, const float* __restrict__ ba,
                                             const float* __restrict__ Wv2, const float* __restrict__ bv2,
                                             const float* __restrict__ Wo2, const float* __restrict__ bo2,
                                             const float* __restrict__ Wo, const float* __restrict__ W1,
                                             const float* __restrict__ W2, const float* __restrict__ Wr,
                                             const float* __restrict__ Wm, const float* __restrict__ br,
                                             const float* __restrict__ bm, const float* __restrict__ objW,
                                             const float* __restrict__ Wq, const float* __restrict__ bq,
                                             const float* __restrict__ Wk, const float* __restrict__ bk,
                                             const float* __restrict__ Wv, const float* __restrict__ bv,
                                             float* __restrict__ cross,
                                             float* __restrict__ Mw,  float* __restrict__ QMw,
                                             float* __restrict__ KMw, float* __restrict__ VMw,
                                             float* __restrict__ qbw, float* __restrict__ kbw,
                                             float* __restrict__ vbw, float* __restrict__ xbw,
                                             float* __restrict__ q0w, float* __restrict__ k0w,
                                             float* __restrict__ v0w, float* __restrict__ x0w,
                                             u16* __restrict__ wob, u16* __restrict__ w1b,
                                             u16* __restrict__ w2b, u16* __restrict__ wrb){
  const int b = blockIdx.x, tid = threadIdx.x;
  if (b == 120){
    __shared__ float Msh[4096];
    __shared__ float bMs[64];
    __shared__ float uS[640];
    __shared__ float x0s[64];
    for (int i = tid; i < 4096; i += 256) wob[i] = f2bu(Wo[i]);
    for (int i = tid; i < 8192; i += 256){ w1b[i] = f2bu(W1[i]); w2b[i] = f2bu(W2[i]); }
    for (int i = tid; i < 1984; i += 256) wrb[i] = f2bu(Wr[i]);
    // stage 1: M, bMs, x0
    for (int idx = tid; idx < 4096; idx += 256){
      int d = idx >> 6, e = idx & 63;
      float acc = 0.f;
      #pragma unroll
      for (int j = 0; j < 31; ++j) acc += Wm[d*31 + j] * Wr[j*64 + e];
      Msh[idx] = acc; Mw[idx] = acc;
    }
    if (tid < 64){
      float acc = bm[tid];
      #pragma unroll
      for (int j = 0; j < 31; ++j) acc += Wm[tid*31 + j] * br[j];
      bMs[tid] = acc + objW[tid*5];
      x0s[tid] = objW[tid*5] + pe_val(0, tid);
    }
    __syncthreads();
    // stage 2: xb table
    for (int idx = tid; idx < 640; idx += 256){
      int p = idx >> 6, d = idx & 63;
      float u = bMs[d] + pe_val(p, d);
      uS[idx] = u; xbw[idx] = u;
    }
    __syncthreads();
    // stage 3: QM, KM, VM
    for (int idx = tid; idx < 4096; idx += 256){
      int d = idx >> 6, e = idx & 63;
      float aq = 0.f, ak = 0.f, av = 0.f;
      #pragma unroll
      for (int j = 0; j < 64; ++j){
        float m = Msh[j*64 + e];
        aq += Wq[d*64 + j]*m; ak += Wk[d*64 + j]*m; av += Wv[d*64 + j]*m;
      }
      QMw[idx] = aq; KMw[idx] = ak; VMw[idx] = av;
    }
    // stage 4: qb/kb/vb tables
    for (int idx = tid; idx < 640; idx += 256){
      int p = idx >> 6, d = idx & 63;
      float aq = bq[d], ak = bk[d], av = bv[d];
      #pragma unroll
      for (int j = 0; j < 64; ++j){
        float u = uS[p*64 + j];
        aq += Wq[d*64 + j]*u; ak += Wk[d*64 + j]*u; av += Wv[d*64 + j]*u;
      }
      qbw[idx] = aq; kbw[idx] = ak; vbw[idx] = av;
    }
    // stage 5: q0,k0,v0,x0
    if (tid < 64){
      float aq = bq[tid], ak = bk[tid], av = bv[tid];
      #pragma unroll
      for (int j = 0; j < 64; ++j){
        float x = x0s[j];
        aq += Wq[tid*64 + j]*x; ak += Wk[tid*64 + j]*x; av += Wv[tid*64 + j]*x;
      }
      q0w[tid] = aq; k0w[tid] = ak; v0w[tid] = av; x0w[tid] = x0s[tid];
    }
    return;
  }
  __shared__ float ash[1024];
  __shared__ float msh[64], tsh[64];
  for (int i = tid; i < 1024; i += 256) ash[i] = audio[b*1024 + i];
  __syncthreads();
  const int w = tid >> 6, lane = tid & 63;
  for (int d = w*16; d < w*16 + 16; ++d){
    const float4* row = (const float4*)(Wa + d*1024);
    float acc = 0.f;
    #pragma unroll
    for (int m = 0; m < 4; ++m){
      float4 wp = row[lane + 64*m];
      int j = 4*(lane + 64*m);
      acc += wp.x*ash[j] + wp.y*ash[j+1] + wp.z*ash[j+2] + wp.w*ash[j+3];
    }
    acc = dpp_sum(acc);
    if (lane == 0) msh[d] = acc + ba[d];
  }
  __syncthreads();
  if (tid < 64){
    const float4* r1 = (const float4*)(Wv2 + tid*64);
    float a = bv2[tid];
    #pragma unroll
    for (int j = 0; j < 16; ++j){ float4 p = r1[j]; a += p.x*msh[4*j] + p.y*msh[4*j+1] + p.z*msh[4*j+2] + p.w*msh[4*j+3]; }
    tsh[tid] = a;
  }
  __syncthreads();
  if (tid < 64){
    const float4* r2 = (const float4*)(Wo2 + tid*64);
    float c = bo2[tid];
    #pragma unroll
    for (int j = 0; j < 16; ++j){ float4 p = r2[j]; c += p.x*tsh[4*j] + p.y*tsh[4*j+1] + p.z*tsh[4*j+2] + p.w*tsh[4*j+3]; }
    cross[b*64 + tid] = c;
  }
}

// ---------- kernel SCAN: SINGLE WAVE, zero barriers, fused qkvx-from-h3 ----------
__global__ __launch_bounds__(64, 1) void k_scan(
    const float* __restrict__ Wo, const float* __restrict__ bo,
    const float* __restrict__ W1, const float* __restrict__ c1,
    const float* __restrict__ W2, const float* __restrict__ c2,
    const float* __restrict__ g1, const float* __restrict__ be1,
    const float* __restrict__ g2, const float* __restrict__ be2,
    const float* __restrict__ g3, const float* __restrict__ be3,
    const float* __restrict__ Mw,  const float* __restrict__ QMw,
    const float* __restrict__ KMw, const float* __restrict__ VMw,
    const float* __restrict__ qbw, const float* __restrict__ kbw,
    const float* __restrict__ vbw, const float* __restrict__ xbw,
    const float* __restrict__ q0w, const float* __restrict__ k0w,
    const float* __restrict__ v0w, const float* __restrict__ x0w,
    const float* __restrict__ cross,
    u16* __restrict__ xw16, u16* __restrict__ Kw16, u16* __restrict__ Vw16)
{
  __shared__ __align__(16) f16 KcS[128*KROW_];   // 17.0 KB (rows 120..127 stay zero)
  __shared__ __align__(16) f16 VcS[D_*VROW_];    // 16.5 KB
  __shared__ __align__(16) f16 xwS[T_*D_];       // 15.0 KB
  __shared__ __align__(16) f16 W1bS[D_*WP_];     // 8.5 KB  W1 rows 64..127
  __shared__ __align__(16) f16 W2aS[D_*WP_];     // W2[:, 0:64]
  __shared__ __align__(16) f16 W2bS[D_*WP_];     // W2[:, 64:128]
  __shared__ __align__(16) f16 MS[D_*WP_];       // M rows
  __shared__ float qbS[640], kbS[640], vbS[640], xbS[640];
  __shared__ __align__(16) f16 sch[256];
  __shared__ __align__(16) f16 qh[64], ath[64], h2h[64], h3h[64];
  __shared__ __align__(16) f16 fsh[128];

  const int i = threadIdx.x;   // one wave

  // register-resident weights (f16 pairs): 5 x 32 = 160 VGPRs
  h2 QM[32], KM[32], VM[32], WOr[32], W1a[32];
  loadrow32(QM,  QMw + i*64);
  loadrow32(KM,  KMw + i*64);
  loadrow32(VM,  VMw + i*64);
  loadrow32(WOr, Wo  + i*64);
  loadrow32(W1a, W1  + i*64);
  const float bo_r = bo[i], c1a = c1[i], c1b = c1[64+i], c2r = c2[i];
  const float g1r = g1[i], b1r = be1[i], g2r = g2[i], b2r = be2[i], g3r = g3[i], b3r = be3[i];
  const float cls_r = cross[119*64 + i];

  // stage LDS weights (f16, stride WP_)
  for (int idx = i; idx < 4096; idx += 64){
    int r = idx >> 6, c = idx & 63;
    W1bS[r*WP_ + c] = (f16)W1[(64+r)*64 + c];
    W2aS[r*WP_ + c] = (f16)W2[r*128 + c];
    W2bS[r*WP_ + c] = (f16)W2[r*128 + 64 + c];
    MS  [r*WP_ + c] = (f16)Mw[r*64 + c];
  }
  for (int idx = i; idx < 640; idx += 64){
    qbS[idx] = qbw[idx]; kbS[idx] = kbw[idx]; vbS[idx] = vbw[idx]; xbS[idx] = xbw[idx];
  }
  { u32* p = (u32*)KcS; for (int idx = i; idx < 128*KROW_/2; idx += 64) p[idx] = 0; }
  { u32* p = (u32*)VcS; for (int idx = i; idx < D_*VROW_/2;  idx += 64) p[idx] = 0; }
  // init t=0 state
  float xr = x0w[i];
  qh[i] = (f16)q0w[i];
  KcS[i] = (f16)k0w[i];
  VcS[i*VROW_] = (f16)v0w[i];
  xwS[i] = (f16)xr;
  WSYNC();

  int pp = 1;  // (t+1) % 10
  for (int t = 0; t < T_-1; ++t){
    // ---- A: scores both heads, positions i and i+64; softmax (no max-sub) ----
    {
      const h8* qv  = (const h8*)qh;
      const h4* kr0 = (const h4*)(KcS + i*KROW_);
      const h4* kr1 = (const h4*)(KcS + (i+64)*KROW_);
      float d00a=0.f,d00b=0.f,d01a=0.f,d01b=0.f,d10a=0.f,d10b=0.f,d11a=0.f,d11b=0.f;
      #pragma unroll
      for (int r = 0; r < 4; ++r){
        h8 ql = qv[r], qhn = qv[4+r];
        h2 ql0=SHV(ql,0,1),  ql1=SHV(ql,2,3),  ql2=SHV(ql,4,5),  ql3=SHV(ql,6,7);
        h2 qh0=SHV(qhn,0,1), qh1=SHV(qhn,2,3), qh2=SHV(qhn,4,5), qh3=SHV(qhn,6,7);
        h4 ka = kr0[2*r],   kb = kr0[2*r+1];
        h4 kc = kr0[8+2*r], kd = kr0[9+2*r];
        h4 ke = kr1[2*r],   kf = kr1[2*r+1];
        h4 kg = kr1[8+2*r], kh = kr1[9+2*r];
        d00a = DOT2(SHV(ka,0,1), ql0, d00a); d00b = DOT2(SHV(ka,2,3), ql1, d00b);
        d00a = DOT2(SHV(kb,0,1), ql2, d00a); d00b = DOT2(SHV(kb,2,3), ql3, d00b);
        d10a = DOT2(SHV(kc,0,1), qh0, d10a); d10b = DOT2(SHV(kc,2,3), qh1, d10b);
        d10a = DOT2(SHV(kd,0,1), qh2, d10a); d10b = DOT2(SHV(kd,2,3), qh3, d10b);
        d01a = DOT2(SHV(ke,0,1), ql0, d01a); d01b = DOT2(SHV(ke,2,3), ql1, d01b);
        d01a = DOT2(SHV(kf,0,1), ql2, d01a); d01b = DOT2(SHV(kf,2,3), ql3, d01b);
        d11a = DOT2(SHV(kg,0,1), qh0, d11a); d11b = DOT2(SHV(kg,2,3), qh1, d11b);
        d11a = DOT2(SHV(kh,0,1), qh2, d11a); d11b = DOT2(SHV(kh,2,3), qh3, d11b);
      }
      const float SC = 0.17677669529663687f;
      int r0 = (t - i) / 10, r1 = (t - i - 64) / 10;
      bool m0 = (i <= t), m1 = (i + 64 <= t);
      float e00 = m0 ? __expf((d00a+d00b)*SC - 0.0625f*(float)r0)     : 0.f;
      float e01 = m1 ? __expf((d01a+d01b)*SC - 0.0625f*(float)r1)     : 0.f;
      float e10 = m0 ? __expf((d10a+d10b)*SC - 0.00390625f*(float)r0) : 0.f;
      float e11 = m1 ? __expf((d11a+d11b)*SC - 0.00390625f*(float)r1) : 0.f;
      float inv0 = 1.f / dpp_sum(e00 + e01);
      float inv1 = 1.f / dpp_sum(e10 + e11);
      sch[i]      = (f16)(e00*inv0);
      sch[64+i]   = (f16)(e01*inv0);
      sch[128+i]  = (f16)(e10*inv1);
      sch[192+i]  = (f16)(e11*inv1);
    }
    WSYNC();
    // ---- C: attn for dim i (head i>>5), all 120 positions ----
    {
      const h8* av = (const h8*)(sch + (i >> 5)*128);
      const h4* vv = (const h4*)(VcS + i*VROW_);
      float p0=0.f,p1=0.f,p2=0.f,p3=0.f;
      #pragma unroll
      for (int r = 0; r < 15; ++r){
        h8 a = av[r];
        h4 va = vv[2*r], vb = vv[2*r+1];
        p0 = DOT2(SHV(va,0,1), SHV(a,0,1), p0);
        p1 = DOT2(SHV(va,2,3), SHV(a,2,3), p1);
        p2 = DOT2(SHV(vb,0,1), SHV(a,4,5), p2);
        p3 = DOT2(SHV(vb,2,3), SHV(a,6,7), p3);
      }
      ath[i] = (f16)((p0+p1)+(p2+p3));
    }
    WSYNC();
    // ---- E: sa = Wo@at + bo ; LN1(x + sa) ; + cross_last ; LN2 ----
    float h2v;
    {
      const h8* av = (const h8*)ath;
      float a0=bo_r, a1=0.f, a2=0.f, a3=0.f;
      #pragma unroll
      for (int r = 0; r < 8; ++r){
        h8 x = av[r];
        a0 = DOT2(WOr[4*r+0], SHV(x,0,1), a0);
        a1 = DOT2(WOr[4*r+1], SHV(x,2,3), a1);
        a2 = DOT2(WOr[4*r+2], SHV(x,4,5), a2);
        a3 = DOT2(WOr[4*r+3], SHV(x,6,7), a3);
      }
      float y = xr + (a0+a1)+(a2+a3);
      float s = dpp_sum(y), s2 = dpp_sum(y*y);
      float m = s*(1.f/64.f), var = fmaxf(s2*(1.f/64.f) - m*m, 0.f);
      float h1 = (y - m)*rsqrtf(var + 1e-5f)*g1r + b1r;
      float z = h1 + cls_r;
      float sz = dpp_sum(z), sz2 = dpp_sum(z*z);
      float mz = sz*(1.f/64.f), vz = fmaxf(sz2*(1.f/64.f) - mz*mz, 0.f);
      h2v = (z - mz)*rsqrtf(vz + 1e-5f)*g2r + b2r;
      h2h[i] = (f16)h2v;
    }
    WSYNC();
    // ---- G: FFN1 rows i (regs) and 64+i (LDS) ----
    {
      const h8* hv = (const h8*)h2h;
      const h4* w1b_ = (const h4*)(W1bS + i*WP_);
      float a0=c1a, a1=0.f, a2=0.f, a3=0.f, b0=c1b, b1=0.f, b2=0.f, b3=0.f;
      #pragma unroll
      for (int r = 0; r < 8; ++r){
        h8 x = hv[r];
        h2 xa=SHV(x,0,1), xb=SHV(x,2,3), xc=SHV(x,4,5), xd=SHV(x,6,7);
        a0 = DOT2(W1a[4*r+0], xa, a0); a1 = DOT2(W1a[4*r+1], xb, a1);
        a2 = DOT2(W1a[4*r+2], xc, a2); a3 = DOT2(W1a[4*r+3], xd, a3);
        h4 wa = w1b_[2*r], wb = w1b_[2*r+1];
        b0 = DOT2(SHV(wa,0,1), xa, b0); b1 = DOT2(SHV(wa,2,3), xb, b1);
        b2 = DOT2(SHV(wb,0,1), xc, b2); b3 = DOT2(SHV(wb,2,3), xd, b3);
      }
      fsh[i]    = (f16)fmaxf((a0+a1)+(a2+a3), 0.f);
      fsh[64+i] = (f16)fmaxf((b0+b1)+(b2+b3), 0.f);
    }
    WSYNC();
    // ---- I: FFN2 (LDS W2) + LN3 ----
    float h3v;
    {
      const h8* fv = (const h8*)fsh;
      const h4* wa_ = (const h4*)(W2aS + i*WP_);
      const h4* wb_ = (const h4*)(W2bS + i*WP_);
      float a0=c2r, a1=0.f, a2=0.f, a3=0.f;
      #pragma unroll
      for (int r = 0; r < 8; ++r){
        h8 x = fv[r];
        h4 p = wa_[2*r], q = wa_[2*r+1];
        a0 = DOT2(SHV(p,0,1), SHV(x,0,1), a0);
        a1 = DOT2(SHV(p,2,3), SHV(x,2,3), a1);
        a2 = DOT2(SHV(q,0,1), SHV(x,4,5), a2);
        a3 = DOT2(SHV(q,2,3), SHV(x,6,7), a3);
      }
      #pragma unroll
      for (int r = 0; r < 8; ++r){
        h8 x = fv[8+r];
        h4 p = wb_[2*r], q = wb_[2*r+1];
        a0 = DOT2(SHV(p,0,1), SHV(x,0,1), a0);
        a1 = DOT2(SHV(p,2,3), SHV(x,2,3), a1);
        a2 = DOT2(SHV(q,0,1), SHV(x,4,5), a2);
        a3 = DOT2(SHV(q,2,3), SHV(x,6,7), a3);
      }
      float y = h2v + (a0+a1)+(a2+a3);
      float s = dpp_sum(y), s2 = dpp_sum(y*y);
      float m = s*(1.f/64.f), var = fmaxf(s2*(1.f/64.f) - m*m, 0.f);
      h3v = (y - m)*rsqrtf(var + 1e-5f)*g3r + b3r;
      h3h[i] = (f16)h3v;
    }
    WSYNC();
    // ---- J: q,k,v,x for t+1 directly from h3 (fused) ----
    {
      const h8* hv3 = (const h8*)h3h;
      const h4* mr_ = (const h4*)(MS + i*WP_);
      float q0=qbS[pp*64+i], q1=0.f, q2=0.f, q3=0.f;
      float k0=kbS[pp*64+i], k1=0.f, k2=0.f, k3=0.f;
      float v0=vbS[pp*64+i], v1=0.f, v2=0.f, v3=0.f;
      float x0=xbS[pp*64+i], x1=0.f, x2=0.f, x3=0.f;
      #pragma unroll
      for (int r = 0; r < 8; ++r){
        h8 x = hv3[r];
        h2 xa=SHV(x,0,1), xb=SHV(x,2,3), xc=SHV(x,4,5), xd=SHV(x,6,7);
        q0 = DOT2(QM[4*r+0], xa, q0); q1 = DOT2(QM[4*r+1], xb, q1);
        q2 = DOT2(QM[4*r+2], xc, q2); q3 = DOT2(QM[4*r+3], xd, q3);
        k0 = DOT2(KM[4*r+0], xa, k0); k1 = DOT2(KM[4*r+1], xb, k1);
        k2 = DOT2(KM[4*r+2], xc, k2); k3 = DOT2(KM[4*r+3], xd, k3);
        v0 = DOT2(VM[4*r+0], xa, v0); v1 = DOT2(VM[4*r+1], xb, v1);
        v2 = DOT2(VM[4*r+2], xc, v2); v3 = DOT2(VM[4*r+3], xd, v3);
        h4 ma = mr_[2*r], mb = mr_[2*r+1];
        x0 = DOT2(SHV(ma,0,1), xa, x0); x1 = DOT2(SHV(ma,2,3), xb, x1);
        x2 = DOT2(SHV(mb,0,1), xc, x2); x3 = DOT2(SHV(mb,2,3), xd, x3);
      }
      float qv_ = (q0+q1)+(q2+q3), kv_ = (k0+k1)+(k2+k3);
      float vv_ = (v0+v1)+(v2+v3), xv_ = (x0+x1)+(x2+x3);
      qh[i] = (f16)qv_;
      KcS[(t+1)*KROW_ + i] = (f16)kv_;
      VcS[i*VROW_ + (t+1)] = (f16)vv_;
      xr = xv_;
      xwS[(t+1)*64 + i] = (f16)xv_;
    }
    WSYNC();
    pp = (pp == 9) ? 0 : pp + 1;
  }
  // ---- dump histories: K/V rows 0..119, x all ----
  {
    const u16* kc = (const u16*)KcS;
    const u16* vc = (const u16*)VcS;
    for (int idx = i; idx < 120*64; idx += 64){
      int t_ = idx >> 6, d = idx & 63;
      Kw16[idx] = kc[t_*KROW_ + d];
      Vw16[idx] = vc[d*VROW_ + t_];
    }
    const u32* xs32 = (const u32*)xwS;
    for (int idx = i; idx < T_*D_/2; idx += 64) ((u32*)xw16)[idx] = xs32[idx];
  }
}

// ---------- kernel FINAL: full pass, one block per row (f16 x/K/V inputs) ----------
__global__ __launch_bounds__(128) void k_final(
    const float* __restrict__ Wq, const float* __restrict__ bq, const float* __restrict__ bo,
    const float* __restrict__ g1, const float* __restrict__ be1,
    const float* __restrict__ g2, const float* __restrict__ be2,
    const float* __restrict__ g3, const float* __restrict__ be3,
    const float* __restrict__ c1, const float* __restrict__ c2, const float* __restrict__ br,
    const u16* __restrict__ wo_b, const u16* __restrict__ w1_b,
    const u16* __restrict__ w2_b, const u16* __restrict__ wr_b,
    const float* __restrict__ cross, const u16* __restrict__ xw16,
    const u16* __restrict__ Kw16, const u16* __restrict__ Vw16,
    float* __restrict__ out)
{
  __shared__ float xs[64], qs[64], at[64], h2s[64], h3s[64], fs[128], sc[256];
  const int irow = blockIdx.x, tid = threadIdx.x;
  const f16* xp = (const f16*)xw16;
  const f16* kp = (const f16*)Kw16;
  const f16* vp = (const f16*)Vw16;
  if (tid < 64) xs[tid] = (float)xp[irow*64 + tid];
  __syncthreads();
  if (tid < 64){
    const float4* wr_ = (const float4*)(Wq + tid*64);
    float acc = bq[tid];
    #pragma unroll
    for (int j = 0; j < 16; ++j){ float4 w = wr_[j]; acc += w.x*xs[4*j] + w.y*xs[4*j+1] + w.z*xs[4*j+2] + w.w*xs[4*j+3]; }
    qs[tid] = acc;
  }
  __syncthreads();
  {
    const int h = tid >> 6, j = tid & 63;
    const float* qh_ = qs + h*32;
    float d0 = 0.f, d1 = 0.f;
    const h4* k0 = (const h4*)(kp + j*64 + h*32);
    #pragma unroll
    for (int w = 0; w < 8; ++w){
      h4 p = k0[w];
      d0 += (float)p.x*qh_[4*w] + (float)p.y*qh_[4*w+1] + (float)p.z*qh_[4*w+2] + (float)p.w*qh_[4*w+3];
    }
    if (j < 56){
      const h4* k1 = (const h4*)(kp + (j+64)*64 + h*32);
      #pragma unroll
      for (int w = 0; w < 8; ++w){
        h4 p = k1[w];
        d1 += (float)p.x*qh_[4*w] + (float)p.y*qh_[4*w+1] + (float)p.z*qh_[4*w+2] + (float)p.w*qh_[4*w+3];
      }
    }
    const float slope = h ? 0.00390625f : 0.0625f;
    float s0 = (j      <= irow) ? d0*0.17677669529663687f - slope*(float)((irow-j)/10)    : -1e30f;
    float s1 = (j + 64 <= irow) ? d1*0.17677669529663687f - slope*(float)((irow-j-64)/10) : -1e30f;
    float m = dpp_max_pos(fmaxf(s0, s1) + 16384.f) - 16384.f;
    float e0 = (j      <= irow) ? __expf(s0 - m) : 0.f;
    float e1 = (j + 64 <= irow) ? __expf(s1 - m) : 0.f;
    float inv = 1.f / dpp_sum(e0 + e1);
    sc[h*128 + j]      = e0*inv;
    sc[h*128 + j + 64] = e1*inv;
  }
  __syncthreads();
  if (tid < 64){
    const float* a = sc + (tid >> 5)*128;
    float a0=0.f,a1=0.f,a2=0.f,a3=0.f;
    #pragma unroll
    for (int jj = 0; jj < 30; ++jj){
      a0 += a[4*jj]   * (float)vp[(4*jj)*64   + tid];
      a1 += a[4*jj+1] * (float)vp[(4*jj+1)*64 + tid];
      a2 += a[4*jj+2] * (float)vp[(4*jj+2)*64 + tid];
      a3 += a[4*jj+3] * (float)vp[(4*jj+3)*64 + tid];
    }
    at[tid] = (a0+a1)+(a2+a3);
  }
  __syncthreads();
  if (tid < 64){
    const u32* orow = (const u32*)(wo_b + tid*64);
    float acc = bo[tid];
    #pragma unroll
    for (int w = 0; w < 32; ++w){ float2 p = bp2(orow[w]); acc += p.x*at[2*w] + p.y*at[2*w+1]; }
    float y = xs[tid] + acc;
    float s = dpp_sum(y), s2 = dpp_sum(y*y);
    float m = s*(1.f/64.f), var = fmaxf(s2*(1.f/64.f) - m*m, 0.f);
    float h1 = (y - m)*rsqrtf(var + 1e-5f)*g1[tid] + be1[tid];
    float z = h1 + cross[irow*64 + tid];
    float sz = dpp_sum(z), sz2 = dpp_sum(z*z);
    float mz = sz*(1.f/64.f), vz = fmaxf(sz2*(1.f/64.f) - mz*mz, 0.f);
    h2s[tid] = (z - mz)*rsqrtf(vz + 1e-5f)*g2[tid] + be2[tid];
  }
  __syncthreads();
  {
    const u32* w1r = (const u32*)(w1_b + tid*64);
    float acc = c1[tid];
    #pragma unroll
    for (int w = 0; w < 32; ++w){ float2 p = bp2(w1r[w]); acc += p.x*h2s[2*w] + p.y*h2s[2*w+1]; }
    fs[tid] = fmaxf(acc, 0.f);
  }
  __syncthreads();
  if (tid < 64){
    const u32* w2r = (const u32*)(w2_b + tid*128);
    float acc = c2[tid];
    #pragma unroll
    for (int w = 0; w < 64; ++w){ float2 p = bp2(w2r[w]); acc += p.x*fs[2*w] + p.y*fs[2*w+1]; }
    float y = h2s[tid] + acc;
    float s = dpp_sum(y), s2 = dpp_sum(y*y);
    float m = s*(1.f/64.f), var = fmaxf(s2*(1.f/64.f) - m*m, 0.f);
    h3s[tid] = (y - m)*rsqrtf(var + 1e-5f)*g3[tid] + be3[tid];
  }
  __syncthreads();
  if (tid < DOUT_){
    const u32* rr = (const u32*)(wr_b + tid*64);
    float acc = br[tid];
    #pragma unroll
    for (int w = 0; w < 32; ++w){ float2 p = bp2(rr[w]); acc += p.x*h3s[2*w] + p.y*h3s[2*w+1]; }
    out[irow*DOUT_ + tid] = acc;
  }
}

extern "C" void kernel_launch(void* const* d_in, const int* in_sizes, int n_in,
                              void* d_out, int out_size, void* d_ws, size_t ws_size,
                              hipStream_t stream){
  const float* audio=(const float*)d_in[0];
  const float* Wa   =(const float*)d_in[1];
  const float* ba   =(const float*)d_in[2];
  const float* objW =(const float*)d_in[3];
  const float* Wq   =(const float*)d_in[4];
  const float* bq   =(const float*)d_in[5];
  const float* Wk   =(const float*)d_in[6];
  const float* bk   =(const float*)d_in[7];
  const float* Wv   =(const float*)d_in[8];
  const float* bv   =(const float*)d_in[9];
  const float* Wo   =(const float*)d_in[10];
  const float* bo   =(const float*)d_in[11];
  const float* Wv2  =(const float*)d_in[12];
  const float* bv2  =(const float*)d_in[13];
  const float* Wo2  =(const float*)d_in[14];
  const float* bo2  =(const float*)d_in[15];
  const float* g1   =(const float*)d_in[16];
  const float* be1  =(const float*)d_in[17];
  const float* g2   =(const float*)d_in[18];
  const float* be2  =(const float*)d_in[19];
  const float* g3   =(const float*)d_in[20];
  const float* be3  =(const float*)d_in[21];
  const float* W1   =(const float*)d_in[22];
  const float* c1   =(const float*)d_in[23];
  const float* W2   =(const float*)d_in[24];
  const float* c2   =(const float*)d_in[25];
  const float* Wr   =(const float*)d_in[26];
  const float* br   =(const float*)d_in[27];
  const float* Wm   =(const float*)d_in[28];
  const float* bm   =(const float*)d_in[29];

  float* ws    = (float*)d_ws;
  float* cross = ws;            // 7680
  float* Mw    = ws + 7680;     // 4096
  float* QMw   = ws + 11776;    // 4096
  float* KMw   = ws + 15872;    // 4096
  float* VMw   = ws + 19968;    // 4096
  float* qbw   = ws + 24064;    // 640
  float* kbw   = ws + 24704;    // 640
  float* vbw   = ws + 25344;    // 640
  float* xbw   = ws + 25984;    // 640
  float* q0w   = ws + 26624;    // 64
  float* k0w   = ws + 26688;    // 64
  float* v0w   = ws + 26752;    // 64
  float* x0w   = ws + 26816;    // 64
  u16* xw16 = (u16*)(ws + 26880);   // 7680 u16
  u16* Kw16 = xw16 + 7680;
  u16* Vw16 = Kw16 + 7680;
  u16* wo_b = Vw16 + 7680;      // 4096
  u16* w1_b = wo_b + 4096;      // 8192
  u16* w2_b = w1_b + 8192;      // 8192
  u16* wr_b = w2_b + 8192;      // 1984
  float* out = (float*)d_out;

  k_pre  <<<dim3(121), dim3(256), 0, stream>>>(audio, Wa, ba, Wv2, bv2, Wo2, bo2,
                                               Wo, W1, W2, Wr, Wm, br, bm, objW,
                                               Wq, bq, Wk, bk, Wv, bv,
                                               cross, Mw, QMw, KMw, VMw,
                                               qbw, kbw, vbw, xbw, q0w, k0w, v0w, x0w,
                                               wo_b, w1_b, w2_b, wr_b);
  k_scan <<<dim3(1),   dim3(64),  0, stream>>>(Wo, bo, W1, c1, W2, c2,
                                               g1, be1, g2, be2, g3, be3,
                                               Mw, QMw, KMw, VMw, qbw, kbw, vbw, xbw,
                                               q0w, k0w, v0w, x0w,
                                               cross, xw16, Kw16, Vw16);
  k_final<<<dim3(120), dim3(128), 0, stream>>>(Wq, bq, bo, g1, be1, g2, be2, g3, be3,
                                               c1, c2, br, wo_b, w1_b, w2_b, wr_b,
                                               cross, xw16, Kw16, Vw16, out);
}

// Round 10
// 501.527 us; speedup vs baseline: 1.1244x; 1.1244x over previous
//
#include <hip/hip_runtime.h>

typedef unsigned short u16;
typedef unsigned int   u32;
typedef _Float16 f16;
typedef f16 h2 __attribute__((ext_vector_type(2)));
typedef f16 h4 __attribute__((ext_vector_type(4)));
typedef f16 h8 __attribute__((ext_vector_type(8)));

#define T_    120
#define D_    64
#define DOUT_ 31
#define KH_   36    // f16 per K half-cache row (72B, 8B-aligned)
#define VH_   124   // f16 per V half-cache row (248B, 8B-aligned)
#define W2P_  132   // W2 LDS row stride (264B, 8B-aligned, 2-way)
#define MP_   68    // M LDS row stride (136B, 8B-aligned, 2-way)

#if defined(__has_builtin)
#if __has_builtin(__builtin_amdgcn_fdot2)
#define DOT2(a,b,c) __builtin_amdgcn_fdot2((a),(b),(c),false)
#endif
#endif
#ifndef DOT2
#define DOT2(a,b,c) ((float)(a).x*(float)(b).x + ((float)(a).y*(float)(b).y + (c)))
#endif
#define SHV(x,i,j) __builtin_shufflevector((x),(x),(i),(j))

__device__ __forceinline__ h2 pk(float a, float b){
#if defined(__has_builtin) && __has_builtin(__builtin_amdgcn_cvt_pkrtz)
  return __builtin_bit_cast(h2, __builtin_amdgcn_cvt_pkrtz(a, b));
#else
  h2 r; r.x = (f16)a; r.y = (f16)b; return r;
#endif
}
__device__ __forceinline__ float2 bp2(u32 u){
  float2 r; r.x = __uint_as_float(u << 16); r.y = __uint_as_float(u & 0xffff0000u); return r;
}
__device__ __forceinline__ u16 f2bu(float f){
  u32 u = __float_as_uint(f);
  u32 r = u + 0x7fffu + ((u >> 16) & 1u);
  return (u16)(r >> 16);
}
#define WSYNC() do{ __asm__ __volatile__("" ::: "memory"); __builtin_amdgcn_wave_barrier(); }while(0)

__device__ __forceinline__ float dpp_sum(float x){
  int t;
  t = __builtin_amdgcn_update_dpp(0, __float_as_int(x), 0x111, 0xf, 0xf, true); x += __int_as_float(t);
  t = __builtin_amdgcn_update_dpp(0, __float_as_int(x), 0x112, 0xf, 0xf, true); x += __int_as_float(t);
  t = __builtin_amdgcn_update_dpp(0, __float_as_int(x), 0x114, 0xf, 0xf, true); x += __int_as_float(t);
  t = __builtin_amdgcn_update_dpp(0, __float_as_int(x), 0x118, 0xf, 0xf, true); x += __int_as_float(t);
  t = __builtin_amdgcn_update_dpp(0, __float_as_int(x), 0x142, 0xf, 0xf, true); x += __int_as_float(t);
  t = __builtin_amdgcn_update_dpp(0, __float_as_int(x), 0x143, 0xf, 0xf, true); x += __int_as_float(t);
  return __int_as_float(__builtin_amdgcn_readlane(__float_as_int(x), 63));
}
__device__ __forceinline__ float dpp_max_pos(float x){   // requires true max > 0 (k_final only)
  int t;
  t = __builtin_amdgcn_update_dpp(0, __float_as_int(x), 0x111, 0xf, 0xf, true); x = fmaxf(x, __int_as_float(t));
  t = __builtin_amdgcn_update_dpp(0, __float_as_int(x), 0x112, 0xf, 0xf, true); x = fmaxf(x, __int_as_float(t));
  t = __builtin_amdgcn_update_dpp(0, __float_as_int(x), 0x114, 0xf, 0xf, true); x = fmaxf(x, __int_as_float(t));
  t = __builtin_amdgcn_update_dpp(0, __float_as_int(x), 0x118, 0xf, 0xf, true); x = fmaxf(x, __int_as_float(t));
  t = __builtin_amdgcn_update_dpp(0, __float_as_int(x), 0x142, 0xf, 0xf, true); x = fmaxf(x, __int_as_float(t));
  t = __builtin_amdgcn_update_dpp(0, __float_as_int(x), 0x143, 0xf, 0xf, true); x = fmaxf(x, __int_as_float(t));
  return __int_as_float(__builtin_amdgcn_readlane(__float_as_int(x), 63));
}
__device__ __forceinline__ float pe_val(int row, int i){
  const float coef = -0.28782313662425574f; // -ln(10000)/32
  int p = row % 10;
  float dv  = __expf((float)(i >> 1) * coef);
  float ang = (float)p * dv;
  return (i & 1) ? __cosf(ang) : __sinf(ang);
}
__device__ __forceinline__ void loadrow32(h2* dst, const float* row){
  #pragma unroll
  for (int r = 0; r < 16; ++r){
    float4 f = ((const float4*)row)[r];
    dst[2*r]   = pk(f.x, f.y);
    dst[2*r+1] = pk(f.z, f.w);
  }
}

// ---------- kernel PRE (identical to round 9) ----------
__global__ __launch_bounds__(256) void k_pre(const float* __restrict__ audio,
                                             const float* __restrict__ Wa, const float* __restrict__ ba,
                                             const float* __restrict__ Wv2, const float* __restrict__ bv2,
                                             const float* __restrict__ Wo2, const float* __restrict__ bo2,
                                             const float* __restrict__ Wo, const float* __restrict__ W1,
                                             const float* __restrict__ W2, const float* __restrict__ Wr,
                                             const float* __restrict__ Wm, const float* __restrict__ br,
                                             const float* __restrict__ bm, const float* __restrict__ objW,
                                             const float* __restrict__ Wq, const float* __restrict__ bq,
                                             const float* __restrict__ Wk, const float* __restrict__ bk,
                                             const float* __restrict__ Wv, const float* __restrict__ bv,
                                             float* __restrict__ cross,
                                             float* __restrict__ Mw,  float* __restrict__ QMw,
                                             float* __restrict__ KMw, float* __restrict__ VMw,
                                             float* __restrict__ qbw, float* __restrict__ kbw,
                                             float* __restrict__ vbw, float* __restrict__ xbw,
                                             float* __restrict__ q0w, float* __restrict__ k0w,
                                             float* __restrict__ v0w, float* __restrict__ x0w,
                                             u16* __restrict__ wob, u16* __restrict__ w1b,
                                             u16* __restrict__ w2b, u16* __restrict__ wrb){
  const int b = blockIdx.x, tid = threadIdx.x;
  if (b == 120){
    __shared__ float Msh[4096];
    __shared__ float bMs[64];
    __shared__ float uS[640];
    __shared__ float x0s[64];
    for (int i = tid; i < 4096; i += 256) wob[i] = f2bu(Wo[i]);
    for (int i = tid; i < 8192; i += 256){ w1b[i] = f2bu(W1[i]); w2b[i] = f2bu(W2[i]); }
    for (int i = tid; i < 1984; i += 256) wrb[i] = f2bu(Wr[i]);
    for (int idx = tid; idx < 4096; idx += 256){
      int d = idx >> 6, e = idx & 63;
      float acc = 0.f;
      #pragma unroll
      for (int j = 0; j < 31; ++j) acc += Wm[d*31 + j] * Wr[j*64 + e];
      Msh[idx] = acc; Mw[idx] = acc;
    }
    if (tid < 64){
      float acc = bm[tid];
      #pragma unroll
      for (int j = 0; j < 31; ++j) acc += Wm[tid*31 + j] * br[j];
      bMs[tid] = acc + objW[tid*5];
      x0s[tid] = objW[tid*5] + pe_val(0, tid);
    }
    __syncthreads();
    for (int idx = tid; idx < 640; idx += 256){
      int p = idx >> 6, d = idx & 63;
      float u = bMs[d] + pe_val(p, d);
      uS[idx] = u; xbw[idx] = u;
    }
    __syncthreads();
    for (int idx = tid; idx < 4096; idx += 256){
      int d = idx >> 6, e = idx & 63;
      float aq = 0.f, ak = 0.f, av = 0.f;
      #pragma unroll
      for (int j = 0; j < 64; ++j){
        float m = Msh[j*64 + e];
        aq += Wq[d*64 + j]*m; ak += Wk[d*64 + j]*m; av += Wv[d*64 + j]*m;
      }
      QMw[idx] = aq; KMw[idx] = ak; VMw[idx] = av;
    }
    for (int idx = tid; idx < 640; idx += 256){
      int p = idx >> 6, d = idx & 63;
      float aq = bq[d], ak = bk[d], av = bv[d];
      #pragma unroll
      for (int j = 0; j < 64; ++j){
        float u = uS[p*64 + j];
        aq += Wq[d*64 + j]*u; ak += Wk[d*64 + j]*u; av += Wv[d*64 + j]*u;
      }
      qbw[idx] = aq; kbw[idx] = ak; vbw[idx] = av;
    }
    if (tid < 64){
      float aq = bq[tid], ak = bk[tid], av = bv[tid];
      #pragma unroll
      for (int j = 0; j < 64; ++j){
        float x = x0s[j];
        aq += Wq[tid*64 + j]*x; ak += Wk[tid*64 + j]*x; av += Wv[tid*64 + j]*x;
      }
      q0w[tid] = aq; k0w[tid] = ak; v0w[tid] = av; x0w[tid] = x0s[tid];
    }
    return;
  }
  __shared__ float ash[1024];
  __shared__ float msh[64], tsh[64];
  for (int i = tid; i < 1024; i += 256) ash[i] = audio[b*1024 + i];
  __syncthreads();
  const int w = tid >> 6, lane = tid & 63;
  for (int d = w*16; d < w*16 + 16; ++d){
    const float4* row = (const float4*)(Wa + d*1024);
    float acc = 0.f;
    #pragma unroll
    for (int m = 0; m < 4; ++m){
      float4 wp = row[lane + 64*m];
      int j = 4*(lane + 64*m);
      acc += wp.x*ash[j] + wp.y*ash[j+1] + wp.z*ash[j+2] + wp.w*ash[j+3];
    }
    acc = dpp_sum(acc);
    if (lane == 0) msh[d] = acc + ba[d];
  }
  __syncthreads();
  if (tid < 64){
    const float4* r1 = (const float4*)(Wv2 + tid*64);
    float a = bv2[tid];
    #pragma unroll
    for (int j = 0; j < 16; ++j){ float4 p = r1[j]; a += p.x*msh[4*j] + p.y*msh[4*j+1] + p.z*msh[4*j+2] + p.w*msh[4*j+3]; }
    tsh[tid] = a;
  }
  __syncthreads();
  if (tid < 64){
    const float4* r2 = (const float4*)(Wo2 + tid*64);
    float c = bo2[tid];
    #pragma unroll
    for (int j = 0; j < 16; ++j){ float4 p = r2[j]; c += p.x*tsh[4*j] + p.y*tsh[4*j+1] + p.z*tsh[4*j+2] + p.w*tsh[4*j+3]; }
    cross[b*64 + tid] = c;
  }
}

// ---------- kernel SCAN: 2 waves, per-head redundant state, 2 barriers/step ----------
__global__ __launch_bounds__(128, 1) void k_scan(
    const float* __restrict__ Wo, const float* __restrict__ bo,
    const float* __restrict__ W1, const float* __restrict__ c1,
    const float* __restrict__ W2, const float* __restrict__ c2,
    const float* __restrict__ g1, const float* __restrict__ be1,
    const float* __restrict__ g2, const float* __restrict__ be2,
    const float* __restrict__ g3, const float* __restrict__ be3,
    const float* __restrict__ Mw,  const float* __restrict__ QMw,
    const float* __restrict__ KMw, const float* __restrict__ VMw,
    const float* __restrict__ qbw, const float* __restrict__ kbw,
    const float* __restrict__ vbw, const float* __restrict__ xbw,
    const float* __restrict__ q0w, const float* __restrict__ k0w,
    const float* __restrict__ v0w, const float* __restrict__ x0w,
    const float* __restrict__ cross,
    u16* __restrict__ xw16, u16* __restrict__ Kw16, u16* __restrict__ Vw16)
{
  __shared__ __align__(16) f16 Khc[2][128*KH_];   // per-head K half-cache (rows 120..127 zero)
  __shared__ __align__(16) f16 Vhc[2][32*VH_];    // per-head V^T half-cache
  __shared__ __align__(16) f16 xwS[T_*D_];
  __shared__ __align__(16) f16 W2S[64*W2P_];
  __shared__ __align__(16) f16 MS[64*MP_];
  __shared__ __align__(16) f16 schS[2][128];
  __shared__ __align__(16) f16 qS[2][32];
  __shared__ __align__(16) f16 atS[2][32];
  __shared__ float saPS[2][64];
  __shared__ __align__(16) f16 h2S[2][64], h3S[2][64];
  __shared__ __align__(16) f16 fS[128];
  __shared__ float qbS[640], kbS[640], vbS[640], xbS[640];

  const int tid = threadIdx.x;
  const int i = tid & 63;
  const int w = tid >> 6;        // wave = head

  // per-wave register weights (144 h2)
  h2 QM[32], KM[32], VM[32], W1h[32], WoH[16];
  loadrow32(QM,  QMw + i*64);
  loadrow32(KM,  KMw + i*64);
  loadrow32(VM,  VMw + i*64);
  loadrow32(W1h, W1 + (w*64 + i)*64);
  {
    const float4* rr = (const float4*)(Wo + i*64 + w*32);
    #pragma unroll
    for (int r = 0; r < 8; ++r){
      float4 f = rr[r];
      WoH[2*r]   = pk(f.x, f.y);
      WoH[2*r+1] = pk(f.z, f.w);
    }
  }
  const float bo_r = bo[i], c1r = c1[w*64 + i], c2r = c2[i];
  const float g1r = g1[i], b1r = be1[i], g2r = g2[i], b2r = be2[i], g3r = g3[i], b3r = be3[i];
  const float cls_r = cross[119*64 + i];

  // stage LDS weights + tables
  for (int idx = tid; idx < 64*128; idx += 128){
    int r = idx >> 7, c = idx & 127;
    W2S[r*W2P_ + c] = (f16)W2[idx];
  }
  for (int idx = tid; idx < 4096; idx += 128){
    int r = idx >> 6, c = idx & 63;
    MS[r*MP_ + c] = (f16)Mw[idx];
  }
  for (int idx = tid; idx < 640; idx += 128){
    qbS[idx] = qbw[idx]; kbS[idx] = kbw[idx]; vbS[idx] = vbw[idx]; xbS[idx] = xbw[idx];
  }
  { u32* p = (u32*)Khc; for (int idx = tid; idx < 2*128*KH_/2; idx += 128) p[idx] = 0; }
  { u32* p = (u32*)Vhc; for (int idx = tid; idx < 2*32*VH_/2;  idx += 128) p[idx] = 0; }
  float xr = x0w[i];
  if ((i >> 5) == w){
    qS[w][i & 31] = (f16)q0w[i];
    Khc[w][i & 31] = (f16)k0w[i];            // row 0
    Vhc[w][(i & 31)*VH_] = (f16)v0w[i];      // pos 0
  }
  if (w == 0) xwS[i] = (f16)xr;
  __syncthreads();

  int pp = 1;  // (t+1) % 10
  for (int t = 0; t < T_-1; ++t){
    // ---- scores (own head): positions i and i+64; softmax (no max-sub) ----
    {
      const h8* qv  = (const h8*)qS[w];
      const h4* kr0 = (const h4*)(Khc[w] + i*KH_);
      const h4* kr1 = (const h4*)(Khc[w] + (i+64)*KH_);
      float d0a=0.f,d0b=0.f,d1a=0.f,d1b=0.f;
      #pragma unroll
      for (int r = 0; r < 4; ++r){
        h8 q = qv[r];
        h2 q0=SHV(q,0,1), q1=SHV(q,2,3), q2=SHV(q,4,5), q3=SHV(q,6,7);
        h4 ka = kr0[2*r], kb = kr0[2*r+1];
        h4 ke = kr1[2*r], kf = kr1[2*r+1];
        d0a = DOT2(SHV(ka,0,1), q0, d0a); d0b = DOT2(SHV(ka,2,3), q1, d0b);
        d0a = DOT2(SHV(kb,0,1), q2, d0a); d0b = DOT2(SHV(kb,2,3), q3, d0b);
        d1a = DOT2(SHV(ke,0,1), q0, d1a); d1b = DOT2(SHV(ke,2,3), q1, d1b);
        d1a = DOT2(SHV(kf,0,1), q2, d1a); d1b = DOT2(SHV(kf,2,3), q3, d1b);
      }
      const float SC = 0.17677669529663687f;
      const float slope = w ? 0.00390625f : 0.0625f;
      int r0 = (t - i) / 10, r1 = (t - i - 64) / 10;
      bool m0 = (i <= t), m1 = (i + 64 <= t);
      float e0 = m0 ? __expf((d0a+d0b)*SC - slope*(float)r0) : 0.f;
      float e1 = m1 ? __expf((d1a+d1b)*SC - slope*(float)r1) : 0.f;
      float inv = 1.f / dpp_sum(e0 + e1);
      schS[w][i]      = (f16)(e0*inv);
      schS[w][64 + i] = (f16)(e1*inv);
    }
    WSYNC();
    // ---- attn (own head): dim d=i>>1, interleaved h4 chunks by lane parity ----
    {
      const int d = i >> 1, ph = i & 1;
      const h4* av = (const h4*)schS[w];
      const h4* vv = (const h4*)(Vhc[w] + d*VH_);
      float p0=0.f, p1=0.f;
      #pragma unroll
      for (int r = 0; r < 15; ++r){
        int c = 2*r + ph;
        h4 a = av[c], v = vv[c];
        p0 = DOT2(SHV(v,0,1), SHV(a,0,1), p0);
        p1 = DOT2(SHV(v,2,3), SHV(a,2,3), p1);
      }
      float p = p0 + p1;
      p += __shfl_xor(p, 1, 64);
      if (ph == 0) atS[w][d] = (f16)p;
    }
    WSYNC();
    // ---- sa partial: Wo[:, w-half] @ at_w ----
    {
      const h8* ar = (const h8*)atS[w];
      float a0=0.f, a1=0.f, a2=0.f, a3=0.f;
      #pragma unroll
      for (int r = 0; r < 4; ++r){
        h8 x = ar[r];
        a0 = DOT2(WoH[4*r+0], SHV(x,0,1), a0);
        a1 = DOT2(WoH[4*r+1], SHV(x,2,3), a1);
        a2 = DOT2(WoH[4*r+2], SHV(x,4,5), a2);
        a3 = DOT2(WoH[4*r+3], SHV(x,6,7), a3);
      }
      saPS[w][i] = (a0+a1)+(a2+a3);
    }
    __syncthreads();   // BARRIER 1: merge sa partials
    // ---- LN1 + LN2 (redundant on both waves) ----
    float h2v;
    {
      float sa = saPS[0][i] + saPS[1][i] + bo_r;
      float y = xr + sa;
      float s = dpp_sum(y), s2 = dpp_sum(y*y);
      float m = s*(1.f/64.f), var = fmaxf(s2*(1.f/64.f) - m*m, 0.f);
      float h1 = (y - m)*rsqrtf(var + 1e-5f)*g1r + b1r;
      float z = h1 + cls_r;
      float sz = dpp_sum(z), sz2 = dpp_sum(z*z);
      float mz = sz*(1.f/64.f), vz = fmaxf(sz2*(1.f/64.f) - mz*mz, 0.f);
      h2v = (z - mz)*rsqrtf(vz + 1e-5f)*g2r + b2r;
      h2S[w][i] = (f16)h2v;
    }
    WSYNC();
    // ---- FFN1 (split): wave w does row w*64 + i ----
    {
      const h8* hv = (const h8*)h2S[w];
      float a0=c1r, a1=0.f, a2=0.f, a3=0.f;
      #pragma unroll
      for (int r = 0; r < 8; ++r){
        h8 x = hv[r];
        a0 = DOT2(W1h[4*r+0], SHV(x,0,1), a0);
        a1 = DOT2(W1h[4*r+1], SHV(x,2,3), a1);
        a2 = DOT2(W1h[4*r+2], SHV(x,4,5), a2);
        a3 = DOT2(W1h[4*r+3], SHV(x,6,7), a3);
      }
      fS[w*64 + i] = (f16)fmaxf((a0+a1)+(a2+a3), 0.f);
    }
    __syncthreads();   // BARRIER 2: merge FFN1 halves
    // ---- FFN2 + LN3 (redundant) ----
    float h3v;
    {
      const h8* fv = (const h8*)fS;
      const h4* wr = (const h4*)(W2S + i*W2P_);
      float a0=c2r, a1=0.f, a2=0.f, a3=0.f;
      #pragma unroll
      for (int r = 0; r < 16; ++r){
        h8 x = fv[r];
        h4 p = wr[2*r], q = wr[2*r+1];
        a0 = DOT2(SHV(p,0,1), SHV(x,0,1), a0);
        a1 = DOT2(SHV(p,2,3), SHV(x,2,3), a1);
        a2 = DOT2(SHV(q,0,1), SHV(x,4,5), a2);
        a3 = DOT2(SHV(q,2,3), SHV(x,6,7), a3);
      }
      float y = h2v + (a0+a1)+(a2+a3);
      float s = dpp_sum(y), s2 = dpp_sum(y*y);
      float m = s*(1.f/64.f), var = fmaxf(s2*(1.f/64.f) - m*m, 0.f);
      h3v = (y - m)*rsqrtf(var + 1e-5f)*g3r + b3r;
      h3S[w][i] = (f16)h3v;
    }
    WSYNC();
    // ---- qkvx from h3 (redundant compute, selective own-head writes) ----
    {
      const h8* hv3 = (const h8*)h3S[w];
      const h4* mr  = (const h4*)(MS + i*MP_);
      float q0=qbS[pp*64+i], q1=0.f, q2=0.f, q3=0.f;
      float k0=kbS[pp*64+i], k1=0.f, k2=0.f, k3=0.f;
      float v0=vbS[pp*64+i], v1=0.f, v2=0.f, v3=0.f;
      float x0=xbS[pp*64+i], x1=0.f, x2=0.f, x3=0.f;
      #pragma unroll
      for (int r = 0; r < 8; ++r){
        h8 x = hv3[r];
        h2 xa=SHV(x,0,1), xb=SHV(x,2,3), xc=SHV(x,4,5), xd=SHV(x,6,7);
        q0 = DOT2(QM[4*r+0], xa, q0); q1 = DOT2(QM[4*r+1], xb, q1);
        q2 = DOT2(QM[4*r+2], xc, q2); q3 = DOT2(QM[4*r+3], xd, q3);
        k0 = DOT2(KM[4*r+0], xa, k0); k1 = DOT2(KM[4*r+1], xb, k1);
        k2 = DOT2(KM[4*r+2], xc, k2); k3 = DOT2(KM[4*r+3], xd, k3);
        v0 = DOT2(VM[4*r+0], xa, v0); v1 = DOT2(VM[4*r+1], xb, v1);
        v2 = DOT2(VM[4*r+2], xc, v2); v3 = DOT2(VM[4*r+3], xd, v3);
        h4 ma = mr[2*r], mb = mr[2*r+1];
        x0 = DOT2(SHV(ma,0,1), xa, x0); x1 = DOT2(SHV(ma,2,3), xb, x1);
        x2 = DOT2(SHV(mb,0,1), xc, x2); x3 = DOT2(SHV(mb,2,3), xd, x3);
      }
      float qv_ = (q0+q1)+(q2+q3), kv_ = (k0+k1)+(k2+k3);
      float vv_ = (v0+v1)+(v2+v3), xv_ = (x0+x1)+(x2+x3);
      if ((i >> 5) == w){
        qS[w][i & 31] = (f16)qv_;
        Khc[w][(t+1)*KH_ + (i & 31)] = (f16)kv_;
        Vhc[w][(i & 31)*VH_ + (t+1)] = (f16)vv_;
      }
      xr = xv_;
      if (w == 0) xwS[(t+1)*64 + i] = (f16)xv_;
    }
    WSYNC();
    pp = (pp == 9) ? 0 : pp + 1;
  }
  __syncthreads();
  // ---- dump histories ----
  {
    for (int idx = tid; idx < 120*64; idx += 128){
      int t_ = idx >> 6, d = idx & 63;
      Kw16[idx] = ((const u16*)Khc[d >> 5])[t_*KH_ + (d & 31)];
      Vw16[idx] = ((const u16*)Vhc[d >> 5])[(d & 31)*VH_ + t_];
    }
    const u32* xs32 = (const u32*)xwS;
    for (int idx = tid; idx < T_*D_/2; idx += 128) ((u32*)xw16)[idx] = xs32[idx];
  }
}

// ---------- kernel FINAL (identical to round 9) ----------
__global__ __launch_bounds__(128) void k_final(
    const float* __restrict__ Wq, const float* __restrict__ bq, const float* __restrict__ bo,
    const float* __restrict__ g1, const float* __restrict__ be1,
    const float* __restrict__ g2, const float* __restrict__ be2,
    const float* __restrict__ g3, const float* __restrict__ be3,
    const float* __restrict__ c1, const float* __restrict__ c2, const float* __restrict__ br,
    const u16* __restrict__ wo_b, const u16* __restrict__ w1_b,
    const u16* __restrict__ w2_b, const u16* __restrict__ wr_b,
    const float* __restrict__ cross, const u16* __restrict__ xw16,
    const u16* __restrict__ Kw16, const u16* __restrict__ Vw16,
    float* __restrict__ out)
{
  __shared__ float xs[64], qs[64], at[64], h2s[64], h3s[64], fs[128], sc[256];
  const int irow = blockIdx.x, tid = threadIdx.x;
  const f16* xp = (const f16*)xw16;
  const f16* kp = (const f16*)Kw16;
  const f16* vp = (const f16*)Vw16;
  if (tid < 64) xs[tid] = (float)xp[irow*64 + tid];
  __syncthreads();
  if (tid < 64){
    const float4* wr_ = (const float4*)(Wq + tid*64);
    float acc = bq[tid];
    #pragma unroll
    for (int j = 0; j < 16; ++j){ float4 w = wr_[j]; acc += w.x*xs[4*j] + w.y*xs[4*j+1] + w.z*xs[4*j+2] + w.w*xs[4*j+3]; }
    qs[tid] = acc;
  }
  __syncthreads();
  {
    const int h = tid >> 6, j = tid & 63;
    const float* qh_ = qs + h*32;
    float d0 = 0.f, d1 = 0.f;
    const h4* k0 = (const h4*)(kp + j*64 + h*32);
    #pragma unroll
    for (int w = 0; w < 8; ++w){
      h4 p = k0[w];
      d0 += (float)p.x*qh_[4*w] + (float)p.y*qh_[4*w+1] + (float)p.z*qh_[4*w+2] + (float)p.w*qh_[4*w+3];
    }
    if (j < 56){
      const h4* k1 = (const h4*)(kp + (j+64)*64 + h*32);
      #pragma unroll
      for (int w = 0; w < 8; ++w){
        h4 p = k1[w];
        d1 += (float)p.x*qh_[4*w] + (float)p.y*qh_[4*w+1] + (float)p.z*qh_[4*w+2] + (float)p.w*qh_[4*w+3];
      }
    }
    const float slope = h ? 0.00390625f : 0.0625f;
    float s0 = (j      <= irow) ? d0*0.17677669529663687f - slope*(float)((irow-j)/10)    : -1e30f;
    float s1 = (j + 64 <= irow) ? d1*0.17677669529663687f - slope*(float)((irow-j-64)/10) : -1e30f;
    float m = dpp_max_pos(fmaxf(s0, s1) + 16384.f) - 16384.f;
    float e0 = (j      <= irow) ? __expf(s0 - m) : 0.f;
    float e1 = (j + 64 <= irow) ? __expf(s1 - m) : 0.f;
    float inv = 1.f / dpp_sum(e0 + e1);
    sc[h*128 + j]      = e0*inv;
    sc[h*128 + j + 64] = e1*inv;
  }
  __syncthreads();
  if (tid < 64){
    const float* a = sc + (tid >> 5)*128;
    float a0=0.f,a1=0.f,a2=0.f,a3=0.f;
    #pragma unroll
    for (int jj = 0; jj < 30; ++jj){
      a0 += a[4*jj]   * (float)vp[(4*jj)*64   + tid];
      a1 += a[4*jj+1] * (float)vp[(4*jj+1)*64 + tid];
      a2 += a[4*jj+2] * (float)vp[(4*jj+2)*64 + tid];
      a3 += a[4*jj+3] * (float)vp[(4*jj+3)*64 + tid];
    }
    at[tid] = (a0+a1)+(a2+a3);
  }
  __syncthreads();
  if (tid < 64){
    const u32* orow = (const u32*)(wo_b + tid*64);
    float acc = bo[tid];
    #pragma unroll
    for (int w = 0; w < 32; ++w){ float2 p = bp2(orow[w]); acc += p.x*at[2*w] + p.y*at[2*w+1]; }
    float y = xs[tid] + acc;
    float s = dpp_sum(y), s2 = dpp_sum(y*y);
    float m = s*(1.f/64.f), var = fmaxf(s2*(1.f/64.f) - m*m, 0.f);
    float h1 = (y - m)*rsqrtf(var + 1e-5f)*g1[tid] + be1[tid];
    float z = h1 + cross[irow*64 + tid];
    float sz = dpp_sum(z), sz2 = dpp_sum(z*z);
    float mz = sz*(1.f/64.f), vz = fmaxf(sz2*(1.f/64.f) - mz*mz, 0.f);
    h2s[tid] = (z - mz)*rsqrtf(vz + 1e-5f)*g2[tid] + be2[tid];
  }
  __syncthreads();
  {
    const u32* w1r = (const u32*)(w1_b + tid*64);
    float acc = c1[tid];
    #pragma unroll
    for (int w = 0; w < 32; ++w){ float2 p = bp2(w1r[w]); acc += p.x*h2s[2*w] + p.y*h2s[2*w+1]; }
    fs[tid] = fmaxf(acc, 0.f);
  }
  __syncthreads();
  if (tid < 64){
    const u32* w2r = (const u32*)(w2_b + tid*128);
    float acc = c2[tid];
    #pragma unroll
    for (int w = 0; w < 64; ++w){ float2 p = bp2(w2r[w]); acc += p.x*fs[2*w] + p.y*fs[2*w+1]; }
    float y = h2s[tid] + acc;
    float s = dpp_sum(y), s2 = dpp_sum(y*y);
    float m = s*(1.f/64.f), var = fmaxf(s2*(1.f/64.f) - m*m, 0.f);
    h3s[tid] = (y - m)*rsqrtf(var + 1e-5f)*g3[tid] + be3[tid];
  }
  __syncthreads();
  if (tid < DOUT_){
    const u32* rr = (const u32*)(wr_b + tid*64);
    float acc = br[tid];
    #pragma unroll
    for (int w = 0; w < 32; ++w){ float2 p = bp2(rr[w]); acc += p.x*h3s[2*w] + p.y*h3s[2*w+1]; }
    out[irow*DOUT_ + tid] = acc;
  }
}

extern "C" void kernel_launch(void* const* d_in, const int* in_sizes, int n_in,
                              void* d_out, int out_size, void* d_ws, size_t ws_size,
                              hipStream_t stream){
  const float* audio=(const float*)d_in[0];
  const float* Wa   =(const float*)d_in[1];
  const float* ba   =(const float*)d_in[2];
  const float* objW =(const float*)d_in[3];
  const float* Wq   =(const float*)d_in[4];
  const float* bq   =(const float*)d_in[5];
  const float* Wk   =(const float*)d_in[6];
  const float* bk   =(const float*)d_in[7];
  const float* Wv   =(const float*)d_in[8];
  const float* bv   =(const float*)d_in[9];
  const float* Wo   =(const float*)d_in[10];
  const float* bo   =(const float*)d_in[11];
  const float* Wv2  =(const float*)d_in[12];
  const float* bv2  =(const float*)d_in[13];
  const float* Wo2  =(const float*)d_in[14];
  const float* bo2  =(const float*)d_in[15];
  const float* g1   =(const float*)d_in[16];
  const float* be1  =(const float*)d_in[17];
  const float* g2   =(const float*)d_in[18];
  const float* be2  =(const float*)d_in[19];
  const float* g3   =(const float*)d_in[20];
  const float* be3  =(const float*)d_in[21];
  const float* W1   =(const float*)d_in[22];
  const float* c1   =(const float*)d_in[23];
  const float* W2   =(const float*)d_in[24];
  const float* c2   =(const float*)d_in[25];
  const float* Wr   =(const float*)d_in[26];
  const float* br   =(const float*)d_in[27];
  const float* Wm   =(const float*)d_in[28];
  const float* bm   =(const float*)d_in[29];

  float* ws    = (float*)d_ws;
  float* cross = ws;            // 7680
  float* Mw    = ws + 7680;     // 4096
  float* QMw   = ws + 11776;    // 4096
  float* KMw   = ws + 15872;    // 4096
  float* VMw   = ws + 19968;    // 4096
  float* qbw   = ws + 24064;    // 640
  float* kbw   = ws + 24704;    // 640
  float* vbw   = ws + 25344;    // 640
  float* xbw   = ws + 25984;    // 640
  float* q0w   = ws + 26624;    // 64
  float* k0w   = ws + 26688;    // 64
  float* v0w   = ws + 26752;    // 64
  float* x0w   = ws + 26816;    // 64
  u16* xw16 = (u16*)(ws + 26880);   // 7680 u16
  u16* Kw16 = xw16 + 7680;
  u16* Vw16 = Kw16 + 7680;
  u16* wo_b = Vw16 + 7680;      // 4096
  u16* w1_b = wo_b + 4096;      // 8192
  u16* w2_b = w1_b + 8192;      // 8192
  u16* wr_b = w2_b + 8192;      // 1984
  float* out = (float*)d_out;

  k_pre  <<<dim3(121), dim3(256), 0, stream>>>(audio, Wa, ba, Wv2, bv2, Wo2, bo2,
                                               Wo, W1, W2, Wr, Wm, br, bm, objW,
                                               Wq, bq, Wk, bk, Wv, bv,
                                               cross, Mw, QMw, KMw, VMw,
                                               qbw, kbw, vbw, xbw, q0w, k0w, v0w, x0w,
                                               wo_b, w1_b, w2_b, wr_b);
  k_scan <<<dim3(1),   dim3(128), 0, stream>>>(Wo, bo, W1, c1, W2, c2,
                                               g1, be1, g2, be2, g3, be3,
                                               Mw, QMw, KMw, VMw, qbw, kbw, vbw, xbw,
                                               q0w, k0w, v0w, x0w,
                                               cross, xw16, Kw16, Vw16);
  k_final<<<dim3(120), dim3(128), 0, stream>>>(Wq, bq, bo, g1, be1, g2, be2, g3, be3,
                                               c1, c2, br, wo_b, w1_b, w2_b, wr_b,
                                               cross, xw16, Kw16, Vw16, out);
}

// Round 11
// 471.468 us; speedup vs baseline: 1.1960x; 1.0638x over previous
//
#include <hip/hip_runtime.h>

typedef unsigned short u16;
typedef unsigned int   u32;
typedef _Float16 f16;
typedef f16 h2 __attribute__((ext_vector_type(2)));
typedef f16 h4 __attribute__((ext_vector_type(4)));
typedef f16 h8 __attribute__((ext_vector_type(8)));

#define T_    120
#define D_    64
#define DOUT_ 31
#define KROW_ 68    // f16/row (conflict-free, measured r7: 476 total)
#define VROW_ 132   // f16/row (conflict-free)
#define W2P_  132   // W2 LDS row stride

#if defined(__has_builtin)
#if __has_builtin(__builtin_amdgcn_fdot2)
#define DOT2(a,b,c) __builtin_amdgcn_fdot2((a),(b),(c),false)
#endif
#endif
#ifndef DOT2
#define DOT2(a,b,c) ((float)(a).x*(float)(b).x + ((float)(a).y*(float)(b).y + (c)))
#endif
#define SHV(x,i,j) __builtin_shufflevector((x),(x),(i),(j))

__device__ __forceinline__ h2 pk(float a, float b){
#if defined(__has_builtin) && __has_builtin(__builtin_amdgcn_cvt_pkrtz)
  return __builtin_bit_cast(h2, __builtin_amdgcn_cvt_pkrtz(a, b));
#else
  h2 r; r.x = (f16)a; r.y = (f16)b; return r;
#endif
}
__device__ __forceinline__ float2 bp2(u32 u){
  float2 r; r.x = __uint_as_float(u << 16); r.y = __uint_as_float(u & 0xffff0000u); return r;
}
__device__ __forceinline__ u16 f2bu(float f){
  u32 u = __float_as_uint(f);
  u32 r = u + 0x7fffu + ((u >> 16) & 1u);
  return (u16)(r >> 16);
}
#define WSYNC() do{ __asm__ __volatile__("" ::: "memory"); __builtin_amdgcn_wave_barrier(); }while(0)

__device__ __forceinline__ float dpp_sum(float x){
  int t;
  t = __builtin_amdgcn_update_dpp(0, __float_as_int(x), 0x111, 0xf, 0xf, true); x += __int_as_float(t);
  t = __builtin_amdgcn_update_dpp(0, __float_as_int(x), 0x112, 0xf, 0xf, true); x += __int_as_float(t);
  t = __builtin_amdgcn_update_dpp(0, __float_as_int(x), 0x114, 0xf, 0xf, true); x += __int_as_float(t);
  t = __builtin_amdgcn_update_dpp(0, __float_as_int(x), 0x118, 0xf, 0xf, true); x += __int_as_float(t);
  t = __builtin_amdgcn_update_dpp(0, __float_as_int(x), 0x142, 0xf, 0xf, true); x += __int_as_float(t);
  t = __builtin_amdgcn_update_dpp(0, __float_as_int(x), 0x143, 0xf, 0xf, true); x += __int_as_float(t);
  return __int_as_float(__builtin_amdgcn_readlane(__float_as_int(x), 63));
}
__device__ __forceinline__ float dpp_max_pos(float x){   // requires true max > 0 (k_final only)
  int t;
  t = __builtin_amdgcn_update_dpp(0, __float_as_int(x), 0x111, 0xf, 0xf, true); x = fmaxf(x, __int_as_float(t));
  t = __builtin_amdgcn_update_dpp(0, __float_as_int(x), 0x112, 0xf, 0xf, true); x = fmaxf(x, __int_as_float(t));
  t = __builtin_amdgcn_update_dpp(0, __float_as_int(x), 0x114, 0xf, 0xf, true); x = fmaxf(x, __int_as_float(t));
  t = __builtin_amdgcn_update_dpp(0, __float_as_int(x), 0x118, 0xf, 0xf, true); x = fmaxf(x, __int_as_float(t));
  t = __builtin_amdgcn_update_dpp(0, __float_as_int(x), 0x142, 0xf, 0xf, true); x = fmaxf(x, __int_as_float(t));
  t = __builtin_amdgcn_update_dpp(0, __float_as_int(x), 0x143, 0xf, 0xf, true); x = fmaxf(x, __int_as_float(t));
  return __int_as_float(__builtin_amdgcn_readlane(__float_as_int(x), 63));
}
__device__ __forceinline__ float pe_val(int row, int i){
  const float coef = -0.28782313662425574f; // -ln(10000)/32
  int p = row % 10;
  float dv  = __expf((float)(i >> 1) * coef);
  float ang = (float)p * dv;
  return (i & 1) ? __cosf(ang) : __sinf(ang);
}
__device__ __forceinline__ void loadrow32(h2* dst, const float* row){
  #pragma unroll
  for (int r = 0; r < 16; ++r){
    float4 f = ((const float4*)row)[r];
    dst[2*r]   = pk(f.x, f.y);
    dst[2*r+1] = pk(f.z, f.w);
  }
}

// ---------- kernel PRE (identical to round 9) ----------
__global__ __launch_bounds__(256) void k_pre(const float* __restrict__ audio,
                                             const float* __restrict__ Wa, const float* __restrict__ ba,
                                             const float* __restrict__ Wv2, const float* __restrict__ bv2,
                                             const float* __restrict__ Wo2, const float* __restrict__ bo2,
                                             const float* __restrict__ Wo, const float* __restrict__ W1,
                                             const float* __restrict__ W2, const float* __restrict__ Wr,
                                             const float* __restrict__ Wm, const float* __restrict__ br,
                                             const float* __restrict__ bm, const float* __restrict__ objW,
                                             const float* __restrict__ Wq, const float* __restrict__ bq,
                                             const float* __restrict__ Wk, const float* __restrict__ bk,
                                             const float* __restrict__ Wv, const float* __restrict__ bv,
                                             float* __restrict__ cross,
                                             float* __restrict__ Mw,  float* __restrict__ QMw,
                                             float* __restrict__ KMw, float* __restrict__ VMw,
                                             float* __restrict__ qbw, float* __restrict__ kbw,
                                             float* __restrict__ vbw, float* __restrict__ xbw,
                                             float* __restrict__ q0w, float* __restrict__ k0w,
                                             float* __restrict__ v0w, float* __restrict__ x0w,
                                             u16* __restrict__ wob, u16* __restrict__ w1b,
                                             u16* __restrict__ w2b, u16* __restrict__ wrb){
  const int b = blockIdx.x, tid = threadIdx.x;
  if (b == 120){
    __shared__ float Msh[4096];
    __shared__ float bMs[64];
    __shared__ float uS[640];
    __shared__ float x0s[64];
    for (int i = tid; i < 4096; i += 256) wob[i] = f2bu(Wo[i]);
    for (int i = tid; i < 8192; i += 256){ w1b[i] = f2bu(W1[i]); w2b[i] = f2bu(W2[i]); }
    for (int i = tid; i < 1984; i += 256) wrb[i] = f2bu(Wr[i]);
    for (int idx = tid; idx < 4096; idx += 256){
      int d = idx >> 6, e = idx & 63;
      float acc = 0.f;
      #pragma unroll
      for (int j = 0; j < 31; ++j) acc += Wm[d*31 + j] * Wr[j*64 + e];
      Msh[idx] = acc; Mw[idx] = acc;
    }
    if (tid < 64){
      float acc = bm[tid];
      #pragma unroll
      for (int j = 0; j < 31; ++j) acc += Wm[tid*31 + j] * br[j];
      bMs[tid] = acc + objW[tid*5];
      x0s[tid] = objW[tid*5] + pe_val(0, tid);
    }
    __syncthreads();
    for (int idx = tid; idx < 640; idx += 256){
      int p = idx >> 6, d = idx & 63;
      float u = bMs[d] + pe_val(p, d);
      uS[idx] = u; xbw[idx] = u;
    }
    __syncthreads();
    for (int idx = tid; idx < 4096; idx += 256){
      int d = idx >> 6, e = idx & 63;
      float aq = 0.f, ak = 0.f, av = 0.f;
      #pragma unroll
      for (int j = 0; j < 64; ++j){
        float m = Msh[j*64 + e];
        aq += Wq[d*64 + j]*m; ak += Wk[d*64 + j]*m; av += Wv[d*64 + j]*m;
      }
      QMw[idx] = aq; KMw[idx] = ak; VMw[idx] = av;
    }
    for (int idx = tid; idx < 640; idx += 256){
      int p = idx >> 6, d = idx & 63;
      float aq = bq[d], ak = bk[d], av = bv[d];
      #pragma unroll
      for (int j = 0; j < 64; ++j){
        float u = uS[p*64 + j];
        aq += Wq[d*64 + j]*u; ak += Wk[d*64 + j]*u; av += Wv[d*64 + j]*u;
      }
      qbw[idx] = aq; kbw[idx] = ak; vbw[idx] = av;
    }
    if (tid < 64){
      float aq = bq[tid], ak = bk[tid], av = bv[tid];
      #pragma unroll
      for (int j = 0; j < 64; ++j){
        float x = x0s[j];
        aq += Wq[tid*64 + j]*x; ak += Wk[tid*64 + j]*x; av += Wv[tid*64 + j]*x;
      }
      q0w[tid] = aq; k0w[tid] = ak; v0w[tid] = av; x0w[tid] = x0s[tid];
    }
    return;
  }
  __shared__ float ash[1024];
  __shared__ float msh[64], tsh[64];
  for (int i = tid; i < 1024; i += 256) ash[i] = audio[b*1024 + i];
  __syncthreads();
  const int w = tid >> 6, lane = tid & 63;
  for (int d = w*16; d < w*16 + 16; ++d){
    const float4* row = (const float4*)(Wa + d*1024);
    float acc = 0.f;
    #pragma unroll
    for (int m = 0; m < 4; ++m){
      float4 wp = row[lane + 64*m];
      int j = 4*(lane + 64*m);
      acc += wp.x*ash[j] + wp.y*ash[j+1] + wp.z*ash[j+2] + wp.w*ash[j+3];
    }
    acc = dpp_sum(acc);
    if (lane == 0) msh[d] = acc + ba[d];
  }
  __syncthreads();
  if (tid < 64){
    const float4* r1 = (const float4*)(Wv2 + tid*64);
    float a = bv2[tid];
    #pragma unroll
    for (int j = 0; j < 16; ++j){ float4 p = r1[j]; a += p.x*msh[4*j] + p.y*msh[4*j+1] + p.z*msh[4*j+2] + p.w*msh[4*j+3]; }
    tsh[tid] = a;
  }
  __syncthreads();
  if (tid < 64){
    const float4* r2 = (const float4*)(Wo2 + tid*64);
    float c = bo2[tid];
    #pragma unroll
    for (int j = 0; j < 16; ++j){ float4 p = r2[j]; c += p.x*tsh[4*j] + p.y*tsh[4*j+1] + p.z*tsh[4*j+2] + p.w*tsh[4*j+3]; }
    cross[b*64 + tid] = c;
  }
}

// ---------- kernel SCAN: 2 waves, r7 layouts + fusion, 4 barriers/step ----------
__global__ __launch_bounds__(128, 1) void k_scan(
    const float* __restrict__ Wo, const float* __restrict__ bo,
    const float* __restrict__ W1, const float* __restrict__ c1,
    const float* __restrict__ W2, const float* __restrict__ c2,
    const float* __restrict__ g1, const float* __restrict__ be1,
    const float* __restrict__ g2, const float* __restrict__ be2,
    const float* __restrict__ g3, const float* __restrict__ be3,
    const float* __restrict__ Mw,  const float* __restrict__ QMw,
    const float* __restrict__ KMw, const float* __restrict__ VMw,
    const float* __restrict__ qbw, const float* __restrict__ kbw,
    const float* __restrict__ vbw, const float* __restrict__ xbw,
    const float* __restrict__ q0w, const float* __restrict__ k0w,
    const float* __restrict__ v0w, const float* __restrict__ x0w,
    const float* __restrict__ cross,
    u16* __restrict__ xw16, u16* __restrict__ Kw16, u16* __restrict__ Vw16)
{
  __shared__ __align__(16) f16 KcS[128*KROW_];   // rows 120..127 stay zero
  __shared__ __align__(16) f16 VcS[D_*VROW_];
  __shared__ __align__(16) f16 xwS[T_*D_];
  __shared__ __align__(16) f16 W2S[64*W2P_];
  __shared__ __align__(16) f16 sch[256];         // head0 [0..127], head1 [128..255]
  __shared__ __align__(16) f16 qh[64];
  __shared__ __align__(16) f16 atP[2][64];       // per-wave attn partials
  __shared__ float saP[2][64];
  __shared__ __align__(16) f16 h2S[2][64], h3S[2][64];
  __shared__ __align__(16) f16 fS[128];
  __shared__ float xf[64];
  __shared__ float qbS[640], kbS[640], vbS[640], xbS[640];

  const int tid = threadIdx.x;
  const int i = tid & 63;
  const int w = tid >> 6;
  const bool w0 = (w == 0);

  // per-wave register weights (128 h2 each):
  //  w0: WoR, W1h (rows 0..63), A=QM, B=VM
  //  w1: WoR, W1h (rows 64..127), A=KM, B=M
  h2 WoR[32], W1h[32], A[32], B[32];
  loadrow32(WoR, Wo + i*64);
  loadrow32(W1h, W1 + (w*64 + i)*64);
  if (w0){
    loadrow32(A, QMw + i*64);
    loadrow32(B, VMw + i*64);
  } else {
    loadrow32(A, KMw + i*64);
    loadrow32(B, Mw + i*64);
  }
  const float bo_r = bo[i], c1r = c1[w*64 + i], c2r = c2[i];
  const float g1r = g1[i], b1r = be1[i], g2r = g2[i], b2r = be2[i], g3r = g3[i], b3r = be3[i];
  const float cls_r = cross[119*64 + i];

  for (int idx = tid; idx < 64*128; idx += 128){
    int r = idx >> 7, c = idx & 127;
    W2S[r*W2P_ + c] = (f16)W2[idx];
  }
  for (int idx = tid; idx < 640; idx += 128){
    qbS[idx] = qbw[idx]; kbS[idx] = kbw[idx]; vbS[idx] = vbw[idx]; xbS[idx] = xbw[idx];
  }
  { u32* p = (u32*)KcS; for (int idx = tid; idx < 128*KROW_/2; idx += 128) p[idx] = 0; }
  { u32* p = (u32*)VcS; for (int idx = tid; idx < D_*VROW_/2;  idx += 128) p[idx] = 0; }
  if (w0){
    qh[i] = (f16)q0w[i];
    VcS[i*VROW_] = (f16)v0w[i];
    xwS[i] = (f16)x0w[i];
  } else {
    KcS[i] = (f16)k0w[i];
    xf[i] = x0w[i];
  }
  __syncthreads();

  int pp = 1;  // (t+1) % 10
  for (int t = 0; t < T_-1; ++t){
    // ---- P1: scores + softmax, wave w = head w (r7 code, no max-sub) ----
    {
      const h8* qv  = (const h8*)(qh + w*32);
      const h4* kr0 = (const h4*)(KcS + i*KROW_ + w*32);
      const h4* kr1 = (const h4*)(KcS + (i+64)*KROW_ + w*32);
      float d0a=0.f,d0b=0.f,d1a=0.f,d1b=0.f;
      #pragma unroll
      for (int r = 0; r < 4; ++r){
        h8 q = qv[r];
        h2 q0=SHV(q,0,1), q1=SHV(q,2,3), q2=SHV(q,4,5), q3=SHV(q,6,7);
        h4 ka = kr0[2*r], kb = kr0[2*r+1];
        h4 ke = kr1[2*r], kf = kr1[2*r+1];
        d0a = DOT2(SHV(ka,0,1), q0, d0a); d0b = DOT2(SHV(ka,2,3), q1, d0b);
        d0a = DOT2(SHV(kb,0,1), q2, d0a); d0b = DOT2(SHV(kb,2,3), q3, d0b);
        d1a = DOT2(SHV(ke,0,1), q0, d1a); d1b = DOT2(SHV(ke,2,3), q1, d1b);
        d1a = DOT2(SHV(kf,0,1), q2, d1a); d1b = DOT2(SHV(kf,2,3), q3, d1b);
      }
      const float SC = 0.17677669529663687f;
      const float slope = w ? 0.00390625f : 0.0625f;
      int r0 = (t - i) / 10, r1 = (t - i - 64) / 10;
      bool m0 = (i <= t), m1 = (i + 64 <= t);
      float e0 = m0 ? __expf((d0a+d0b)*SC - slope*(float)r0) : 0.f;
      float e1 = m1 ? __expf((d1a+d1b)*SC - slope*(float)r1) : 0.f;
      float inv = 1.f / dpp_sum(e0 + e1);
      sch[w*128 + i]      = (f16)(e0*inv);
      sch[w*128 + 64 + i] = (f16)(e1*inv);
    }
    __syncthreads();   // B1: sch both heads visible
    // ---- P2: attn partial (wave w = positions w*64..w*64+63) + Wo@partial ----
    {
      const h8* av = (const h8*)(sch + (i >> 5)*128) + w*8;
      const h4* vv = (const h4*)(VcS + i*VROW_) + w*16;
      float p0=0.f,p1=0.f,p2=0.f,p3=0.f;
      #pragma unroll
      for (int r = 0; r < 8; ++r){
        h8 a = av[r];
        h4 va = vv[2*r], vb = vv[2*r+1];
        p0 = DOT2(SHV(va,0,1), SHV(a,0,1), p0);
        p1 = DOT2(SHV(va,2,3), SHV(a,2,3), p1);
        p2 = DOT2(SHV(vb,0,1), SHV(a,4,5), p2);
        p3 = DOT2(SHV(vb,2,3), SHV(a,6,7), p3);
      }
      atP[w][i] = (f16)((p0+p1)+(p2+p3));
      WSYNC();
      const h8* ar = (const h8*)atP[w];
      float a0=0.f, a1=0.f, a2=0.f, a3=0.f;
      #pragma unroll
      for (int r = 0; r < 8; ++r){
        h8 x = ar[r];
        a0 = DOT2(WoR[4*r+0], SHV(x,0,1), a0);
        a1 = DOT2(WoR[4*r+1], SHV(x,2,3), a1);
        a2 = DOT2(WoR[4*r+2], SHV(x,4,5), a2);
        a3 = DOT2(WoR[4*r+3], SHV(x,6,7), a3);
      }
      saP[w][i] = (a0+a1)+(a2+a3);
    }
    __syncthreads();   // B2: merge sa partials
    // ---- P3: LN1 + LN2 (redundant both waves, bit-identical) ----
    float h2v;
    {
      float sa = saP[0][i] + saP[1][i] + bo_r;
      float y = xf[i] + sa;
      float s = dpp_sum(y), s2 = dpp_sum(y*y);
      float m = s*(1.f/64.f), var = fmaxf(s2*(1.f/64.f) - m*m, 0.f);
      float h1 = (y - m)*rsqrtf(var + 1e-5f)*g1r + b1r;
      float z = h1 + cls_r;
      float sz = dpp_sum(z), sz2 = dpp_sum(z*z);
      float mz = sz*(1.f/64.f), vz = fmaxf(sz2*(1.f/64.f) - mz*mz, 0.f);
      h2v = (z - mz)*rsqrtf(vz + 1e-5f)*g2r + b2r;
      h2S[w][i] = (f16)h2v;
    }
    WSYNC();
    // ---- P4: FFN1 split (wave w: row w*64+i) ----
    {
      const h8* hv = (const h8*)h2S[w];
      float a0=c1r, a1=0.f, a2=0.f, a3=0.f;
      #pragma unroll
      for (int r = 0; r < 8; ++r){
        h8 x = hv[r];
        a0 = DOT2(W1h[4*r+0], SHV(x,0,1), a0);
        a1 = DOT2(W1h[4*r+1], SHV(x,2,3), a1);
        a2 = DOT2(W1h[4*r+2], SHV(x,4,5), a2);
        a3 = DOT2(W1h[4*r+3], SHV(x,6,7), a3);
      }
      fS[w*64 + i] = (f16)fmaxf((a0+a1)+(a2+a3), 0.f);
    }
    __syncthreads();   // B3: merge FFN1 halves
    // ---- P5: FFN2 + LN3 (redundant both waves) ----
    {
      const h8* fv = (const h8*)fS;
      const h4* wr = (const h4*)(W2S + i*W2P_);
      float a0=c2r, a1=0.f, a2=0.f, a3=0.f;
      #pragma unroll
      for (int r = 0; r < 16; ++r){
        h8 x = fv[r];
        h4 p = wr[2*r], q = wr[2*r+1];
        a0 = DOT2(SHV(p,0,1), SHV(x,0,1), a0);
        a1 = DOT2(SHV(p,2,3), SHV(x,2,3), a1);
        a2 = DOT2(SHV(q,0,1), SHV(x,4,5), a2);
        a3 = DOT2(SHV(q,2,3), SHV(x,6,7), a3);
      }
      float y = h2v + (a0+a1)+(a2+a3);
      float s = dpp_sum(y), s2 = dpp_sum(y*y);
      float m = s*(1.f/64.f), var = fmaxf(s2*(1.f/64.f) - m*m, 0.f);
      float h3v = (y - m)*rsqrtf(var + 1e-5f)*g3r + b3r;
      h3S[w][i] = (f16)h3v;
    }
    WSYNC();
    // ---- P6: split qkvx from h3: w0 -> q(A)+v(B); w1 -> k(A)+x(B=M) ----
    {
      const h8* hv3 = (const h8*)h3S[w];
      float a0, b0;
      if (w0){ a0 = qbS[pp*64+i]; b0 = vbS[pp*64+i]; }
      else   { a0 = kbS[pp*64+i]; b0 = xbS[pp*64+i]; }
      float a1=0.f,a2=0.f,a3=0.f, b1=0.f,b2=0.f,b3=0.f;
      #pragma unroll
      for (int r = 0; r < 8; ++r){
        h8 x = hv3[r];
        h2 xa=SHV(x,0,1), xb=SHV(x,2,3), xc=SHV(x,4,5), xd=SHV(x,6,7);
        a0 = DOT2(A[4*r+0], xa, a0); a1 = DOT2(A[4*r+1], xb, a1);
        a2 = DOT2(A[4*r+2], xc, a2); a3 = DOT2(A[4*r+3], xd, a3);
        b0 = DOT2(B[4*r+0], xa, b0); b1 = DOT2(B[4*r+1], xb, b1);
        b2 = DOT2(B[4*r+2], xc, b2); b3 = DOT2(B[4*r+3], xd, b3);
      }
      float av_ = (a0+a1)+(a2+a3), bv_ = (b0+b1)+(b2+b3);
      if (w0){
        qh[i] = (f16)av_;
        VcS[i*VROW_ + (t+1)] = (f16)bv_;
      } else {
        KcS[(t+1)*KROW_ + i] = (f16)av_;
        xf[i] = bv_;
        xwS[(t+1)*64 + i] = (f16)bv_;
      }
    }
    __syncthreads();   // B4: qh/Kc/Vc/xf visible for next step
    pp = (pp == 9) ? 0 : pp + 1;
  }
  // ---- dump histories ----
  {
    const u16* kc = (const u16*)KcS;
    const u16* vc = (const u16*)VcS;
    for (int idx = tid; idx < 120*64; idx += 128){
      int t_ = idx >> 6, d = idx & 63;
      Kw16[idx] = kc[t_*KROW_ + d];
      Vw16[idx] = vc[d*VROW_ + t_];
    }
    const u32* xs32 = (const u32*)xwS;
    for (int idx = tid; idx < T_*D_/2; idx += 128) ((u32*)xw16)[idx] = xs32[idx];
  }
}

// ---------- kernel FINAL (identical to round 9) ----------
__global__ __launch_bounds__(128) void k_final(
    const float* __restrict__ Wq, const float* __restrict__ bq, const float* __restrict__ bo,
    const float* __restrict__ g1, const float* __restrict__ be1,
    const float* __restrict__ g2, const float* __restrict__ be2,
    const float* __restrict__ g3, const float* __restrict__ be3,
    const float* __restrict__ c1, const float* __restrict__ c2, const float* __restrict__ br,
    const u16* __restrict__ wo_b, const u16* __restrict__ w1_b,
    const u16* __restrict__ w2_b, const u16* __restrict__ wr_b,
    const float* __restrict__ cross, const u16* __restrict__ xw16,
    const u16* __restrict__ Kw16, const u16* __restrict__ Vw16,
    float* __restrict__ out)
{
  __shared__ float xs[64], qs[64], at[64], h2s[64], h3s[64], fs[128], sc[256];
  const int irow = blockIdx.x, tid = threadIdx.x;
  const f16* xp = (const f16*)xw16;
  const f16* kp = (const f16*)Kw16;
  const f16* vp = (const f16*)Vw16;
  if (tid < 64) xs[tid] = (float)xp[irow*64 + tid];
  __syncthreads();
  if (tid < 64){
    const float4* wr_ = (const float4*)(Wq + tid*64);
    float acc = bq[tid];
    #pragma unroll
    for (int j = 0; j < 16; ++j){ float4 w = wr_[j]; acc += w.x*xs[4*j] + w.y*xs[4*j+1] + w.z*xs[4*j+2] + w.w*xs[4*j+3]; }
    qs[tid] = acc;
  }
  __syncthreads();
  {
    const int h = tid >> 6, j = tid & 63;
    const float* qh_ = qs + h*32;
    float d0 = 0.f, d1 = 0.f;
    const h4* k0 = (const h4*)(kp + j*64 + h*32);
    #pragma unroll
    for (int w = 0; w < 8; ++w){
      h4 p = k0[w];
      d0 += (float)p.x*qh_[4*w] + (float)p.y*qh_[4*w+1] + (float)p.z*qh_[4*w+2] + (float)p.w*qh_[4*w+3];
    }
    if (j < 56){
      const h4* k1 = (const h4*)(kp + (j+64)*64 + h*32);
      #pragma unroll
      for (int w = 0; w < 8; ++w){
        h4 p = k1[w];
        d1 += (float)p.x*qh_[4*w] + (float)p.y*qh_[4*w+1] + (float)p.z*qh_[4*w+2] + (float)p.w*qh_[4*w+3];
      }
    }
    const float slope = h ? 0.00390625f : 0.0625f;
    float s0 = (j      <= irow) ? d0*0.17677669529663687f - slope*(float)((irow-j)/10)    : -1e30f;
    float s1 = (j + 64 <= irow) ? d1*0.17677669529663687f - slope*(float)((irow-j-64)/10) : -1e30f;
    float m = dpp_max_pos(fmaxf(s0, s1) + 16384.f) - 16384.f;
    float e0 = (j      <= irow) ? __expf(s0 - m) : 0.f;
    float e1 = (j + 64 <= irow) ? __expf(s1 - m) : 0.f;
    float inv = 1.f / dpp_sum(e0 + e1);
    sc[h*128 + j]      = e0*inv;
    sc[h*128 + j + 64] = e1*inv;
  }
  __syncthreads();
  if (tid < 64){
    const float* a = sc + (tid >> 5)*128;
    float a0=0.f,a1=0.f,a2=0.f,a3=0.f;
    #pragma unroll
    for (int jj = 0; jj < 30; ++jj){
      a0 += a[4*jj]   * (float)vp[(4*jj)*64   + tid];
      a1 += a[4*jj+1] * (float)vp[(4*jj+1)*64 + tid];
      a2 += a[4*jj+2] * (float)vp[(4*jj+2)*64 + tid];
      a3 += a[4*jj+3] * (float)vp[(4*jj+3)*64 + tid];
    }
    at[tid] = (a0+a1)+(a2+a3);
  }
  __syncthreads();
  if (tid < 64){
    const u32* orow = (const u32*)(wo_b + tid*64);
    float acc = bo[tid];
    #pragma unroll
    for (int w = 0; w < 32; ++w){ float2 p = bp2(orow[w]); acc += p.x*at[2*w] + p.y*at[2*w+1]; }
    float y = xs[tid] + acc;
    float s = dpp_sum(y), s2 = dpp_sum(y*y);
    float m = s*(1.f/64.f), var = fmaxf(s2*(1.f/64.f) - m*m, 0.f);
    float h1 = (y - m)*rsqrtf(var + 1e-5f)*g1[tid] + be1[tid];
    float z = h1 + cross[irow*64 + tid];
    float sz = dpp_sum(z), sz2 = dpp_sum(z*z);
    float mz = sz*(1.f/64.f), vz = fmaxf(sz2*(1.f/64.f) - mz*mz, 0.f);
    h2s[tid] = (z - mz)*rsqrtf(vz + 1e-5f)*g2[tid] + be2[tid];
  }
  __syncthreads();
  {
    const u32* w1r = (const u32*)(w1_b + tid*64);
    float acc = c1[tid];
    #pragma unroll
    for (int w = 0; w < 32; ++w){ float2 p = bp2(w1r[w]); acc += p.x*h2s[2*w] + p.y*h2s[2*w+1]; }
    fs[tid] = fmaxf(acc, 0.f);
  }
  __syncthreads();
  if (tid < 64){
    const u32* w2r = (const u32*)(w2_b + tid*128);
    float acc = c2[tid];
    #pragma unroll
    for (int w = 0; w < 64; ++w){ float2 p = bp2(w2r[w]); acc += p.x*fs[2*w] + p.y*fs[2*w+1]; }
    float y = h2s[tid] + acc;
    float s = dpp_sum(y), s2 = dpp_sum(y*y);
    float m = s*(1.f/64.f), var = fmaxf(s2*(1.f/64.f) - m*m, 0.f);
    h3s[tid] = (y - m)*rsqrtf(var + 1e-5f)*g3[tid] + be3[tid];
  }
  __syncthreads();
  if (tid < DOUT_){
    const u32* rr = (const u32*)(wr_b + tid*64);
    float acc = br[tid];
    #pragma unroll
    for (int w = 0; w < 32; ++w){ float2 p = bp2(rr[w]); acc += p.x*h3s[2*w] + p.y*h3s[2*w+1]; }
    out[irow*DOUT_ + tid] = acc;
  }
}

extern "C" void kernel_launch(void* const* d_in, const int* in_sizes, int n_in,
                              void* d_out, int out_size, void* d_ws, size_t ws_size,
                              hipStream_t stream){
  const float* audio=(const float*)d_in[0];
  const float* Wa   =(const float*)d_in[1];
  const float* ba   =(const float*)d_in[2];
  const float* objW =(const float*)d_in[3];
  const float* Wq   =(const float*)d_in[4];
  const float* bq   =(const float*)d_in[5];
  const float* Wk   =(const float*)d_in[6];
  const float* bk   =(const float*)d_in[7];
  const float* Wv   =(const float*)d_in[8];
  const float* bv   =(const float*)d_in[9];
  const float* Wo   =(const float*)d_in[10];
  const float* bo   =(const float*)d_in[11];
  const float* Wv2  =(const float*)d_in[12];
  const float* bv2  =(const float*)d_in[13];
  const float* Wo2  =(const float*)d_in[14];
  const float* bo2  =(const float*)d_in[15];
  const float* g1   =(const float*)d_in[16];
  const float* be1  =(const float*)d_in[17];
  const float* g2   =(const float*)d_in[18];
  const float* be2  =(const float*)d_in[19];
  const float* g3   =(const float*)d_in[20];
  const float* be3  =(const float*)d_in[21];
  const float* W1   =(const float*)d_in[22];
  const float* c1   =(const float*)d_in[23];
  const float* W2   =(const float*)d_in[24];
  const float* c2   =(const float*)d_in[25];
  const float* Wr   =(const float*)d_in[26];
  const float* br   =(const float*)d_in[27];
  const float* Wm   =(const float*)d_in[28];
  const float* bm   =(const float*)d_in[29];

  float* ws    = (float*)d_ws;
  float* cross = ws;            // 7680
  float* Mw    = ws + 7680;     // 4096
  float* QMw   = ws + 11776;    // 4096
  float* KMw   = ws + 15872;    // 4096
  float* VMw   = ws + 19968;    // 4096
  float* qbw   = ws + 24064;    // 640
  float* kbw   = ws + 24704;    // 640
  float* vbw   = ws + 25344;    // 640
  float* xbw   = ws + 25984;    // 640
  float* q0w   = ws + 26624;    // 64
  float* k0w   = ws + 26688;    // 64
  float* v0w   = ws + 26752;    // 64
  float* x0w   = ws + 26816;    // 64
  u16* xw16 = (u16*)(ws + 26880);   // 7680 u16
  u16* Kw16 = xw16 + 7680;
  u16* Vw16 = Kw16 + 7680;
  u16* wo_b = Vw16 + 7680;      // 4096
  u16* w1_b = wo_b + 4096;      // 8192
  u16* w2_b = w1_b + 8192;      // 8192
  u16* wr_b = w2_b + 8192;      // 1984
  float* out = (float*)d_out;

  k_pre  <<<dim3(121), dim3(256), 0, stream>>>(audio, Wa, ba, Wv2, bv2, Wo2, bo2,
                                               Wo, W1, W2, Wr, Wm, br, bm, objW,
                                               Wq, bq, Wk, bk, Wv, bv,
                                               cross, Mw, QMw, KMw, VMw,
                                               qbw, kbw, vbw, xbw, q0w, k0w, v0w, x0w,
                                               wo_b, w1_b, w2_b, wr_b);
  k_scan <<<dim3(1),   dim3(128), 0, stream>>>(Wo, bo, W1, c1, W2, c2,
                                               g1, be1, g2, be2, g3, be3,
                                               Mw, QMw, KMw, VMw, qbw, kbw, vbw, xbw,
                                               q0w, k0w, v0w, x0w,
                                               cross, xw16, Kw16, Vw16);
  k_final<<<dim3(120), dim3(128), 0, stream>>>(Wq, bq, bo, g1, be1, g2, be2, g3, be3,
                                               c1, c2, br, wo_b, w1_b, w2_b, wr_b,
                                               cross, xw16, Kw16, Vw16, out);
}

// Round 12
// 390.816 us; speedup vs baseline: 1.4429x; 1.2064x over previous
//
#include <hip/hip_runtime.h>

typedef unsigned short u16;
typedef unsigned int   u32;
typedef _Float16 f16;
typedef f16 h2 __attribute__((ext_vector_type(2)));
typedef f16 h4 __attribute__((ext_vector_type(4)));
typedef f16 h8 __attribute__((ext_vector_type(8)));

#define T_    120
#define D_    64
#define DOUT_ 31
#define KROW_ 68    // f16/row (conflict-free, measured r7/r11)
#define VROW_ 132   // f16/row
#define W2P_  132   // W2 LDS row stride

#if defined(__has_builtin)
#if __has_builtin(__builtin_amdgcn_fdot2)
#define DOT2(a,b,c) __builtin_amdgcn_fdot2((a),(b),(c),false)
#endif
#endif
#ifndef DOT2
#define DOT2(a,b,c) ((float)(a).x*(float)(b).x + ((float)(a).y*(float)(b).y + (c)))
#endif
#define SHV(x,i,j) __builtin_shufflevector((x),(x),(i),(j))

__device__ __forceinline__ h2 pk(float a, float b){
#if defined(__has_builtin) && __has_builtin(__builtin_amdgcn_cvt_pkrtz)
  return __builtin_bit_cast(h2, __builtin_amdgcn_cvt_pkrtz(a, b));
#else
  h2 r; r.x = (f16)a; r.y = (f16)b; return r;
#endif
}
__device__ __forceinline__ float2 bp2(u32 u){
  float2 r; r.x = __uint_as_float(u << 16); r.y = __uint_as_float(u & 0xffff0000u); return r;
}
__device__ __forceinline__ u16 f2bu(float f){
  u32 u = __float_as_uint(f);
  u32 r = u + 0x7fffu + ((u >> 16) & 1u);
  return (u16)(r >> 16);
}
#define WSYNC() do{ __asm__ __volatile__("" ::: "memory"); __builtin_amdgcn_wave_barrier(); }while(0)

__device__ __forceinline__ float dpp_sum(float x){
  int t;
  t = __builtin_amdgcn_update_dpp(0, __float_as_int(x), 0x111, 0xf, 0xf, true); x += __int_as_float(t);
  t = __builtin_amdgcn_update_dpp(0, __float_as_int(x), 0x112, 0xf, 0xf, true); x += __int_as_float(t);
  t = __builtin_amdgcn_update_dpp(0, __float_as_int(x), 0x114, 0xf, 0xf, true); x += __int_as_float(t);
  t = __builtin_amdgcn_update_dpp(0, __float_as_int(x), 0x118, 0xf, 0xf, true); x += __int_as_float(t);
  t = __builtin_amdgcn_update_dpp(0, __float_as_int(x), 0x142, 0xf, 0xf, true); x += __int_as_float(t);
  t = __builtin_amdgcn_update_dpp(0, __float_as_int(x), 0x143, 0xf, 0xf, true); x += __int_as_float(t);
  return __int_as_float(__builtin_amdgcn_readlane(__float_as_int(x), 63));
}
__device__ __forceinline__ float dpp_max_pos(float x){   // requires true max > 0 (k_final only)
  int t;
  t = __builtin_amdgcn_update_dpp(0, __float_as_int(x), 0x111, 0xf, 0xf, true); x = fmaxf(x, __int_as_float(t));
  t = __builtin_amdgcn_update_dpp(0, __float_as_int(x), 0x112, 0xf, 0xf, true); x = fmaxf(x, __int_as_float(t));
  t = __builtin_amdgcn_update_dpp(0, __float_as_int(x), 0x114, 0xf, 0xf, true); x = fmaxf(x, __int_as_float(t));
  t = __builtin_amdgcn_update_dpp(0, __float_as_int(x), 0x118, 0xf, 0xf, true); x = fmaxf(x, __int_as_float(t));
  t = __builtin_amdgcn_update_dpp(0, __float_as_int(x), 0x142, 0xf, 0xf, true); x = fmaxf(x, __int_as_float(t));
  t = __builtin_amdgcn_update_dpp(0, __float_as_int(x), 0x143, 0xf, 0xf, true); x = fmaxf(x, __int_as_float(t));
  return __int_as_float(__builtin_amdgcn_readlane(__float_as_int(x), 63));
}
__device__ __forceinline__ float pe_val(int row, int i){
  const float coef = -0.28782313662425574f; // -ln(10000)/32
  int p = row % 10;
  float dv  = __expf((float)(i >> 1) * coef);
  float ang = (float)p * dv;
  return (i & 1) ? __cosf(ang) : __sinf(ang);
}
__device__ __forceinline__ void loadrow32(h2* dst, const float* row){
  #pragma unroll
  for (int r = 0; r < 16; ++r){
    float4 f = ((const float4*)row)[r];
    dst[2*r]   = pk(f.x, f.y);
    dst[2*r+1] = pk(f.z, f.w);
  }
}

// ---------- kernel PRE: blocks 0-119 mem+cross; block 120: bf16 prep + M + tables + x0 ----------
__global__ __launch_bounds__(256) void k_pre(const float* __restrict__ audio,
                                             const float* __restrict__ Wa, const float* __restrict__ ba,
                                             const float* __restrict__ Wv2, const float* __restrict__ bv2,
                                             const float* __restrict__ Wo2, const float* __restrict__ bo2,
                                             const float* __restrict__ Wo, const float* __restrict__ W1,
                                             const float* __restrict__ W2, const float* __restrict__ Wr,
                                             const float* __restrict__ Wm, const float* __restrict__ br,
                                             const float* __restrict__ bm, const float* __restrict__ objW,
                                             float* __restrict__ cross,
                                             float* __restrict__ Mw, float* __restrict__ xbw,
                                             float* __restrict__ x0w,
                                             u16* __restrict__ wob, u16* __restrict__ w1b,
                                             u16* __restrict__ w2b, u16* __restrict__ wrb){
  const int b = blockIdx.x, tid = threadIdx.x;
  if (b == 120){
    __shared__ float bMs[64];
    for (int i = tid; i < 4096; i += 256) wob[i] = f2bu(Wo[i]);
    for (int i = tid; i < 8192; i += 256){ w1b[i] = f2bu(W1[i]); w2b[i] = f2bu(W2[i]); }
    for (int i = tid; i < 1984; i += 256) wrb[i] = f2bu(Wr[i]);
    for (int idx = tid; idx < 4096; idx += 256){
      int d = idx >> 6, e = idx & 63;
      float acc = 0.f;
      #pragma unroll
      for (int j = 0; j < 31; ++j) acc += Wm[d*31 + j] * Wr[j*64 + e];
      Mw[idx] = acc;
    }
    if (tid < 64){
      float acc = bm[tid];
      #pragma unroll
      for (int j = 0; j < 31; ++j) acc += Wm[tid*31 + j] * br[j];
      bMs[tid] = acc + objW[tid*5];
      x0w[tid] = objW[tid*5] + pe_val(0, tid);
    }
    __syncthreads();
    for (int idx = tid; idx < 640; idx += 256){
      int p = idx >> 6, d = idx & 63;
      xbw[idx] = bMs[d] + pe_val(p, d);
    }
    return;
  }
  __shared__ float ash[1024];
  __shared__ float msh[64], tsh[64];
  for (int i = tid; i < 1024; i += 256) ash[i] = audio[b*1024 + i];
  __syncthreads();
  const int w = tid >> 6, lane = tid & 63;
  for (int d = w*16; d < w*16 + 16; ++d){
    const float4* row = (const float4*)(Wa + d*1024);
    float acc = 0.f;
    #pragma unroll
    for (int m = 0; m < 4; ++m){
      float4 wp = row[lane + 64*m];
      int j = 4*(lane + 64*m);
      acc += wp.x*ash[j] + wp.y*ash[j+1] + wp.z*ash[j+2] + wp.w*ash[j+3];
    }
    acc = dpp_sum(acc);
    if (lane == 0) msh[d] = acc + ba[d];
  }
  __syncthreads();
  if (tid < 64){
    const float4* r1 = (const float4*)(Wv2 + tid*64);
    float a = bv2[tid];
    #pragma unroll
    for (int j = 0; j < 16; ++j){ float4 p = r1[j]; a += p.x*msh[4*j] + p.y*msh[4*j+1] + p.z*msh[4*j+2] + p.w*msh[4*j+3]; }
    tsh[tid] = a;
  }
  __syncthreads();
  if (tid < 64){
    const float4* r2 = (const float4*)(Wo2 + tid*64);
    float c = bo2[tid];
    #pragma unroll
    for (int j = 0; j < 16; ++j){ float4 p = r2[j]; c += p.x*tsh[4*j] + p.y*tsh[4*j+1] + p.z*tsh[4*j+2] + p.w*tsh[4*j+3]; }
    cross[b*64 + tid] = c;
  }
}

// ---------- kernel PRE2: parallel fusion products (needs Mw, xbw, x0w) ----------
__global__ __launch_bounds__(256) void k_pre2(const float* __restrict__ Wq, const float* __restrict__ bq,
                                              const float* __restrict__ Wk, const float* __restrict__ bk,
                                              const float* __restrict__ Wv, const float* __restrict__ bv,
                                              const float* __restrict__ Mw, const float* __restrict__ xbw,
                                              const float* __restrict__ x0w,
                                              float* __restrict__ QMw, float* __restrict__ KMw,
                                              float* __restrict__ VMw,
                                              float* __restrict__ qbw, float* __restrict__ kbw,
                                              float* __restrict__ vbw,
                                              float* __restrict__ q0w, float* __restrict__ k0w,
                                              float* __restrict__ v0w){
  const int gid = blockIdx.x*256 + threadIdx.x, stride = gridDim.x*256;
  for (int idx = gid; idx < 4096; idx += stride){
    int d = idx >> 6, e = idx & 63;
    float aq = 0.f, ak = 0.f, av = 0.f;
    #pragma unroll 8
    for (int j = 0; j < 64; ++j){
      float m = Mw[j*64 + e];
      aq += Wq[d*64 + j]*m; ak += Wk[d*64 + j]*m; av += Wv[d*64 + j]*m;
    }
    QMw[idx] = aq; KMw[idx] = ak; VMw[idx] = av;
  }
  for (int idx = gid; idx < 640; idx += stride){
    int p = idx >> 6, d = idx & 63;
    float aq = bq[d], ak = bk[d], av = bv[d];
    #pragma unroll 8
    for (int j = 0; j < 64; ++j){
      float u = xbw[p*64 + j];
      aq += Wq[d*64 + j]*u; ak += Wk[d*64 + j]*u; av += Wv[d*64 + j]*u;
    }
    qbw[idx] = aq; kbw[idx] = ak; vbw[idx] = av;
  }
  for (int idx = gid; idx < 64; idx += stride){
    float aq = bq[idx], ak = bk[idx], av = bv[idx];
    #pragma unroll 8
    for (int j = 0; j < 64; ++j){
      float x = x0w[j];
      aq += Wq[idx*64 + j]*x; ak += Wk[idx*64 + j]*x; av += Wv[idx*64 + j]*x;
    }
    q0w[idx] = aq; k0w[idx] = ak; v0w[idx] = av;
  }
}

// ---------- kernel SCAN: 2 waves, head-split attention, 3 barriers/step ----------
__global__ __launch_bounds__(128, 1) void k_scan(
    const float* __restrict__ Wo, const float* __restrict__ bo,
    const float* __restrict__ W1, const float* __restrict__ c1,
    const float* __restrict__ W2, const float* __restrict__ c2,
    const float* __restrict__ g1, const float* __restrict__ be1,
    const float* __restrict__ g2, const float* __restrict__ be2,
    const float* __restrict__ g3, const float* __restrict__ be3,
    const float* __restrict__ Mw,  const float* __restrict__ QMw,
    const float* __restrict__ KMw, const float* __restrict__ VMw,
    const float* __restrict__ qbw, const float* __restrict__ kbw,
    const float* __restrict__ vbw, const float* __restrict__ xbw,
    const float* __restrict__ q0w, const float* __restrict__ k0w,
    const float* __restrict__ v0w, const float* __restrict__ x0w,
    const float* __restrict__ cross,
    u16* __restrict__ xw16, u16* __restrict__ Kw16, u16* __restrict__ Vw16)
{
  __shared__ __align__(16) f16 KcS[128*KROW_];   // rows 120..127 stay zero
  __shared__ __align__(16) f16 VcS[D_*VROW_];
  __shared__ __align__(16) f16 xwS[T_*D_];
  __shared__ __align__(16) f16 W2S[64*W2P_];
  __shared__ __align__(16) f16 sch[256];         // head0 [0..127], head1 [128..255]
  __shared__ __align__(16) f16 qh[64];
  __shared__ __align__(16) f16 atF[64];          // full attn vector (disjoint halves)
  __shared__ __align__(16) f16 h2S[2][64], h3S[2][64];
  __shared__ __align__(16) f16 fS[128];
  __shared__ float xf[64];
  __shared__ float qbS[640], kbS[640], vbS[640], xbS[640];

  const int tid = threadIdx.x;
  const int i = tid & 63;
  const int w = tid >> 6;
  const bool w0 = (w == 0);

  // per-wave register weights (128 h2 each):
  //  w0: WoR, W1h (rows 0..63), A=QM, B=VM
  //  w1: WoR, W1h (rows 64..127), A=KM, B=M
  h2 WoR[32], W1h[32], A[32], B[32];
  loadrow32(WoR, Wo + i*64);
  loadrow32(W1h, W1 + (w*64 + i)*64);
  if (w0){
    loadrow32(A, QMw + i*64);
    loadrow32(B, VMw + i*64);
  } else {
    loadrow32(A, KMw + i*64);
    loadrow32(B, Mw + i*64);
  }
  const float bo_r = bo[i], c1r = c1[w*64 + i], c2r = c2[i];
  const float g1r = g1[i], b1r = be1[i], g2r = g2[i], b2r = be2[i], g3r = g3[i], b3r = be3[i];
  const float cls_r = cross[119*64 + i];

  for (int idx = tid; idx < 64*128; idx += 128){
    int r = idx >> 7, c = idx & 127;
    W2S[r*W2P_ + c] = (f16)W2[idx];
  }
  for (int idx = tid; idx < 640; idx += 128){
    qbS[idx] = qbw[idx]; kbS[idx] = kbw[idx]; vbS[idx] = vbw[idx]; xbS[idx] = xbw[idx];
  }
  { u32* p = (u32*)KcS; for (int idx = tid; idx < 128*KROW_/2; idx += 128) p[idx] = 0; }
  { u32* p = (u32*)VcS; for (int idx = tid; idx < D_*VROW_/2;  idx += 128) p[idx] = 0; }
  if (w0){
    qh[i] = (f16)q0w[i];
    VcS[i*VROW_] = (f16)v0w[i];
    xwS[i] = (f16)x0w[i];
  } else {
    KcS[i] = (f16)k0w[i];
    xf[i] = x0w[i];
  }
  __syncthreads();

  int pp = 1;  // (t+1) % 10
  for (int t = 0; t < T_-1; ++t){
    // ---- P1: scores + softmax, wave w = head w (no max-sub) ----
    {
      const h8* qv  = (const h8*)(qh + w*32);
      const h4* kr0 = (const h4*)(KcS + i*KROW_ + w*32);
      const h4* kr1 = (const h4*)(KcS + (i+64)*KROW_ + w*32);
      float d0a=0.f,d0b=0.f,d1a=0.f,d1b=0.f;
      #pragma unroll
      for (int r = 0; r < 4; ++r){
        h8 q = qv[r];
        h2 q0=SHV(q,0,1), q1=SHV(q,2,3), q2=SHV(q,4,5), q3=SHV(q,6,7);
        h4 ka = kr0[2*r], kb = kr0[2*r+1];
        h4 ke = kr1[2*r], kf = kr1[2*r+1];
        d0a = DOT2(SHV(ka,0,1), q0, d0a); d0b = DOT2(SHV(ka,2,3), q1, d0b);
        d0a = DOT2(SHV(kb,0,1), q2, d0a); d0b = DOT2(SHV(kb,2,3), q3, d0b);
        d1a = DOT2(SHV(ke,0,1), q0, d1a); d1b = DOT2(SHV(ke,2,3), q1, d1b);
        d1a = DOT2(SHV(kf,0,1), q2, d1a); d1b = DOT2(SHV(kf,2,3), q3, d1b);
      }
      const float SC = 0.17677669529663687f;
      const float slope = w ? 0.00390625f : 0.0625f;
      int r0 = (t - i) / 10, r1 = (t - i - 64) / 10;
      bool m0 = (i <= t), m1 = (i + 64 <= t);
      float e0 = m0 ? __expf((d0a+d0b)*SC - slope*(float)r0) : 0.f;
      float e1 = m1 ? __expf((d1a+d1b)*SC - slope*(float)r1) : 0.f;
      float inv = 1.f / dpp_sum(e0 + e1);
      sch[w*128 + i]      = (f16)(e0*inv);
      sch[w*128 + 64 + i] = (f16)(e1*inv);
    }
    WSYNC();   // own-wave sch handoff
    // ---- P2: attn own head (32 dims, paired lanes over 120 positions) ----
    {
      const int dl = i >> 1, ph = i & 1;
      const int d  = w*32 + dl;
      const h4* av = (const h4*)(sch + w*128);
      const h4* vv = (const h4*)(VcS + d*VROW_);
      float p0 = 0.f, p1 = 0.f;
      #pragma unroll
      for (int r = 0; r < 15; ++r){
        int c = 2*r + ph;
        h4 a = av[c], v = vv[c];
        p0 = DOT2(SHV(v,0,1), SHV(a,0,1), p0);
        p1 = DOT2(SHV(v,2,3), SHV(a,2,3), p1);
      }
      float p = p0 + p1;
      p += __shfl_xor(p, 1, 64);
      if (ph == 0) atF[d] = (f16)p;
    }
    __syncthreads();   // B1: atF full
    // ---- P3: sa = Wo@atF + bo (full, redundant) ; LN1 ; +cross_last ; LN2 ----
    float h2v;
    {
      const h8* ar = (const h8*)atF;
      float a0=bo_r, a1=0.f, a2=0.f, a3=0.f;
      #pragma unroll
      for (int r = 0; r < 8; ++r){
        h8 x = ar[r];
        a0 = DOT2(WoR[4*r+0], SHV(x,0,1), a0);
        a1 = DOT2(WoR[4*r+1], SHV(x,2,3), a1);
        a2 = DOT2(WoR[4*r+2], SHV(x,4,5), a2);
        a3 = DOT2(WoR[4*r+3], SHV(x,6,7), a3);
      }
      float y = xf[i] + (a0+a1)+(a2+a3);
      float s = dpp_sum(y), s2 = dpp_sum(y*y);
      float m = s*(1.f/64.f), var = fmaxf(s2*(1.f/64.f) - m*m, 0.f);
      float h1 = (y - m)*rsqrtf(var + 1e-5f)*g1r + b1r;
      float z = h1 + cls_r;
      float sz = dpp_sum(z), sz2 = dpp_sum(z*z);
      float mz = sz*(1.f/64.f), vz = fmaxf(sz2*(1.f/64.f) - mz*mz, 0.f);
      h2v = (z - mz)*rsqrtf(vz + 1e-5f)*g2r + b2r;
      h2S[w][i] = (f16)h2v;
    }
    WSYNC();
    // ---- P4: FFN1 split (wave w: row w*64+i) ----
    {
      const h8* hv = (const h8*)h2S[w];
      float a0=c1r, a1=0.f, a2=0.f, a3=0.f;
      #pragma unroll
      for (int r = 0; r < 8; ++r){
        h8 x = hv[r];
        a0 = DOT2(W1h[4*r+0], SHV(x,0,1), a0);
        a1 = DOT2(W1h[4*r+1], SHV(x,2,3), a1);
        a2 = DOT2(W1h[4*r+2], SHV(x,4,5), a2);
        a3 = DOT2(W1h[4*r+3], SHV(x,6,7), a3);
      }
      fS[w*64 + i] = (f16)fmaxf((a0+a1)+(a2+a3), 0.f);
    }
    __syncthreads();   // B2: merge FFN1 halves
    // ---- P5: FFN2 + LN3 (redundant both waves) ----
    {
      const h8* fv = (const h8*)fS;
      const h4* wr = (const h4*)(W2S + i*W2P_);
      float a0=c2r, a1=0.f, a2=0.f, a3=0.f;
      #pragma unroll
      for (int r = 0; r < 16; ++r){
        h8 x = fv[r];
        h4 p = wr[2*r], q = wr[2*r+1];
        a0 = DOT2(SHV(p,0,1), SHV(x,0,1), a0);
        a1 = DOT2(SHV(p,2,3), SHV(x,2,3), a1);
        a2 = DOT2(SHV(q,0,1), SHV(x,4,5), a2);
        a3 = DOT2(SHV(q,2,3), SHV(x,6,7), a3);
      }
      float y = h2v + (a0+a1)+(a2+a3);
      float s = dpp_sum(y), s2 = dpp_sum(y*y);
      float m = s*(1.f/64.f), var = fmaxf(s2*(1.f/64.f) - m*m, 0.f);
      float h3v = (y - m)*rsqrtf(var + 1e-5f)*g3r + b3r;
      h3S[w][i] = (f16)h3v;
    }
    WSYNC();
    // ---- P6: split qkvx from h3: w0 -> q(A)+v(B); w1 -> k(A)+x(B=M) ----
    {
      const h8* hv3 = (const h8*)h3S[w];
      float a0, b0;
      if (w0){ a0 = qbS[pp*64+i]; b0 = vbS[pp*64+i]; }
      else   { a0 = kbS[pp*64+i]; b0 = xbS[pp*64+i]; }
      float a1=0.f,a2=0.f,a3=0.f, b1=0.f,b2=0.f,b3=0.f;
      #pragma unroll
      for (int r = 0; r < 8; ++r){
        h8 x = hv3[r];
        h2 xa=SHV(x,0,1), xb=SHV(x,2,3), xc=SHV(x,4,5), xd=SHV(x,6,7);
        a0 = DOT2(A[4*r+0], xa, a0); a1 = DOT2(A[4*r+1], xb, a1);
        a2 = DOT2(A[4*r+2], xc, a2); a3 = DOT2(A[4*r+3], xd, a3);
        b0 = DOT2(B[4*r+0], xa, b0); b1 = DOT2(B[4*r+1], xb, b1);
        b2 = DOT2(B[4*r+2], xc, b2); b3 = DOT2(B[4*r+3], xd, b3);
      }
      float av_ = (a0+a1)+(a2+a3), bv_ = (b0+b1)+(b2+b3);
      if (w0){
        qh[i] = (f16)av_;
        VcS[i*VROW_ + (t+1)] = (f16)bv_;
      } else {
        KcS[(t+1)*KROW_ + i] = (f16)av_;
        xf[i] = bv_;
        xwS[(t+1)*64 + i] = (f16)bv_;
      }
    }
    __syncthreads();   // B3: qh/Kc/Vc/xf visible for next step
    pp = (pp == 9) ? 0 : pp + 1;
  }
  // ---- dump histories ----
  {
    const u16* kc = (const u16*)KcS;
    const u16* vc = (const u16*)VcS;
    for (int idx = tid; idx < 120*64; idx += 128){
      int t_ = idx >> 6, d = idx & 63;
      Kw16[idx] = kc[t_*KROW_ + d];
      Vw16[idx] = vc[d*VROW_ + t_];
    }
    const u32* xs32 = (const u32*)xwS;
    for (int idx = tid; idx < T_*D_/2; idx += 128) ((u32*)xw16)[idx] = xs32[idx];
  }
}

// ---------- kernel FINAL (unchanged) ----------
__global__ __launch_bounds__(128) void k_final(
    const float* __restrict__ Wq, const float* __restrict__ bq, const float* __restrict__ bo,
    const float* __restrict__ g1, const float* __restrict__ be1,
    const float* __restrict__ g2, const float* __restrict__ be2,
    const float* __restrict__ g3, const float* __restrict__ be3,
    const float* __restrict__ c1, const float* __restrict__ c2, const float* __restrict__ br,
    const u16* __restrict__ wo_b, const u16* __restrict__ w1_b,
    const u16* __restrict__ w2_b, const u16* __restrict__ wr_b,
    const float* __restrict__ cross, const u16* __restrict__ xw16,
    const u16* __restrict__ Kw16, const u16* __restrict__ Vw16,
    float* __restrict__ out)
{
  __shared__ float xs[64], qs[64], at[64], h2s[64], h3s[64], fs[128], sc[256];
  const int irow = blockIdx.x, tid = threadIdx.x;
  const f16* xp = (const f16*)xw16;
  const f16* kp = (const f16*)Kw16;
  const f16* vp = (const f16*)Vw16;
  if (tid < 64) xs[tid] = (float)xp[irow*64 + tid];
  __syncthreads();
  if (tid < 64){
    const float4* wr_ = (const float4*)(Wq + tid*64);
    float acc = bq[tid];
    #pragma unroll
    for (int j = 0; j < 16; ++j){ float4 w = wr_[j]; acc += w.x*xs[4*j] + w.y*xs[4*j+1] + w.z*xs[4*j+2] + w.w*xs[4*j+3]; }
    qs[tid] = acc;
  }
  __syncthreads();
  {
    const int h = tid >> 6, j = tid & 63;
    const float* qh_ = qs + h*32;
    float d0 = 0.f, d1 = 0.f;
    const h4* k0 = (const h4*)(kp + j*64 + h*32);
    #pragma unroll
    for (int w = 0; w < 8; ++w){
      h4 p = k0[w];
      d0 += (float)p.x*qh_[4*w] + (float)p.y*qh_[4*w+1] + (float)p.z*qh_[4*w+2] + (float)p.w*qh_[4*w+3];
    }
    if (j < 56){
      const h4* k1 = (const h4*)(kp + (j+64)*64 + h*32);
      #pragma unroll
      for (int w = 0; w < 8; ++w){
        h4 p = k1[w];
        d1 += (float)p.x*qh_[4*w] + (float)p.y*qh_[4*w+1] + (float)p.z*qh_[4*w+2] + (float)p.w*qh_[4*w+3];
      }
    }
    const float slope = h ? 0.00390625f : 0.0625f;
    float s0 = (j      <= irow) ? d0*0.17677669529663687f - slope*(float)((irow-j)/10)    : -1e30f;
    float s1 = (j + 64 <= irow) ? d1*0.17677669529663687f - slope*(float)((irow-j-64)/10) : -1e30f;
    float m = dpp_max_pos(fmaxf(s0, s1) + 16384.f) - 16384.f;
    float e0 = (j      <= irow) ? __expf(s0 - m) : 0.f;
    float e1 = (j + 64 <= irow) ? __expf(s1 - m) : 0.f;
    float inv = 1.f / dpp_sum(e0 + e1);
    sc[h*128 + j]      = e0*inv;
    sc[h*128 + j + 64] = e1*inv;
  }
  __syncthreads();
  if (tid < 64){
    const float* a = sc + (tid >> 5)*128;
    float a0=0.f,a1=0.f,a2=0.f,a3=0.f;
    #pragma unroll
    for (int jj = 0; jj < 30; ++jj){
      a0 += a[4*jj]   * (float)vp[(4*jj)*64   + tid];
      a1 += a[4*jj+1] * (float)vp[(4*jj+1)*64 + tid];
      a2 += a[4*jj+2] * (float)vp[(4*jj+2)*64 + tid];
      a3 += a[4*jj+3] * (float)vp[(4*jj+3)*64 + tid];
    }
    at[tid] = (a0+a1)+(a2+a3);
  }
  __syncthreads();
  if (tid < 64){
    const u32* orow = (const u32*)(wo_b + tid*64);
    float acc = bo[tid];
    #pragma unroll
    for (int w = 0; w < 32; ++w){ float2 p = bp2(orow[w]); acc += p.x*at[2*w] + p.y*at[2*w+1]; }
    float y = xs[tid] + acc;
    float s = dpp_sum(y), s2 = dpp_sum(y*y);
    float m = s*(1.f/64.f), var = fmaxf(s2*(1.f/64.f) - m*m, 0.f);
    float h1 = (y - m)*rsqrtf(var + 1e-5f)*g1[tid] + be1[tid];
    float z = h1 + cross[irow*64 + tid];
    float sz = dpp_sum(z), sz2 = dpp_sum(z*z);
    float mz = sz*(1.f/64.f), vz = fmaxf(sz2*(1.f/64.f) - mz*mz, 0.f);
    h2s[tid] = (z - mz)*rsqrtf(vz + 1e-5f)*g2[tid] + be2[tid];
  }
  __syncthreads();
  {
    const u32* w1r = (const u32*)(w1_b + tid*64);
    float acc = c1[tid];
    #pragma unroll
    for (int w = 0; w < 32; ++w){ float2 p = bp2(w1r[w]); acc += p.x*h2s[2*w] + p.y*h2s[2*w+1]; }
    fs[tid] = fmaxf(acc, 0.f);
  }
  __syncthreads();
  if (tid < 64){
    const u32* w2r = (const u32*)(w2_b + tid*128);
    float acc = c2[tid];
    #pragma unroll
    for (int w = 0; w < 64; ++w){ float2 p = bp2(w2r[w]); acc += p.x*fs[2*w] + p.y*fs[2*w+1]; }
    float y = h2s[tid] + acc;
    float s = dpp_sum(y), s2 = dpp_sum(y*y);
    float m = s*(1.f/64.f), var = fmaxf(s2*(1.f/64.f) - m*m, 0.f);
    h3s[tid] = (y - m)*rsqrtf(var + 1e-5f)*g3[tid] + be3[tid];
  }
  __syncthreads();
  if (tid < DOUT_){
    const u32* rr = (const u32*)(wr_b + tid*64);
    float acc = br[tid];
    #pragma unroll
    for (int w = 0; w < 32; ++w){ float2 p = bp2(rr[w]); acc += p.x*h3s[2*w] + p.y*h3s[2*w+1]; }
    out[irow*DOUT_ + tid] = acc;
  }
}

extern "C" void kernel_launch(void* const* d_in, const int* in_sizes, int n_in,
                              void* d_out, int out_size, void* d_ws, size_t ws_size,
                              hipStream_t stream){
  const float* audio=(const float*)d_in[0];
  const float* Wa   =(const float*)d_in[1];
  const float* ba   =(const float*)d_in[2];
  const float* objW =(const float*)d_in[3];
  const float* Wq   =(const float*)d_in[4];
  const float* bq   =(const float*)d_in[5];
  const float* Wk   =(const float*)d_in[6];
  const float* bk   =(const float*)d_in[7];
  const float* Wv   =(const float*)d_in[8];
  const float* bv   =(const float*)d_in[9];
  const float* Wo   =(const float*)d_in[10];
  const float* bo   =(const float*)d_in[11];
  const float* Wv2  =(const float*)d_in[12];
  const float* bv2  =(const float*)d_in[13];
  const float* Wo2  =(const float*)d_in[14];
  const float* bo2  =(const float*)d_in[15];
  const float* g1   =(const float*)d_in[16];
  const float* be1  =(const float*)d_in[17];
  const float* g2   =(const float*)d_in[18];
  const float* be2  =(const float*)d_in[19];
  const float* g3   =(const float*)d_in[20];
  const float* be3  =(const float*)d_in[21];
  const float* W1   =(const float*)d_in[22];
  const float* c1   =(const float*)d_in[23];
  const float* W2   =(const float*)d_in[24];
  const float* c2   =(const float*)d_in[25];
  const float* Wr   =(const float*)d_in[26];
  const float* br   =(const float*)d_in[27];
  const float* Wm   =(const float*)d_in[28];
  const float* bm   =(const float*)d_in[29];

  float* ws    = (float*)d_ws;
  float* cross = ws;            // 7680
  float* Mw    = ws + 7680;     // 4096
  float* QMw   = ws + 11776;    // 4096
  float* KMw   = ws + 15872;    // 4096
  float* VMw   = ws + 19968;    // 4096
  float* qbw   = ws + 24064;    // 640
  float* kbw   = ws + 24704;    // 640
  float* vbw   = ws + 25344;    // 640
  float* xbw   = ws + 25984;    // 640
  float* q0w   = ws + 26624;    // 64
  float* k0w   = ws + 26688;    // 64
  float* v0w   = ws + 26752;    // 64
  float* x0w   = ws + 26816;    // 64
  u16* xw16 = (u16*)(ws + 26880);   // 7680 u16
  u16* Kw16 = xw16 + 7680;
  u16* Vw16 = Kw16 + 7680;
  u16* wo_b = Vw16 + 7680;      // 4096
  u16* w1_b = wo_b + 4096;      // 8192
  u16* w2_b = w1_b + 8192;      // 8192
  u16* wr_b = w2_b + 8192;      // 1984
  float* out = (float*)d_out;

  k_pre  <<<dim3(121), dim3(256), 0, stream>>>(audio, Wa, ba, Wv2, bv2, Wo2, bo2,
                                               Wo, W1, W2, Wr, Wm, br, bm, objW,
                                               cross, Mw, xbw, x0w,
                                               wo_b, w1_b, w2_b, wr_b);
  k_pre2 <<<dim3(17),  dim3(256), 0, stream>>>(Wq, bq, Wk, bk, Wv, bv,
                                               Mw, xbw, x0w,
                                               QMw, KMw, VMw, qbw, kbw, vbw,
                                               q0w, k0w, v0w);
  k_scan <<<dim3(1),   dim3(128), 0, stream>>>(Wo, bo, W1, c1, W2, c2,
                                               g1, be1, g2, be2, g3, be3,
                                               Mw, QMw, KMw, VMw, qbw, kbw, vbw, xbw,
                                               q0w, k0w, v0w, x0w,
                                               cross, xw16, Kw16, Vw16);
  k_final<<<dim3(120), dim3(128), 0, stream>>>(Wq, bq, bo, g1, be1, g2, be2, g3, be3,
                                               c1, c2, br, wo_b, w1_b, w2_b, wr_b,
                                               cross, xw16, Kw16, Vw16, out);
}